// Round 20
// baseline (124.616 us; speedup 1.0000x reference)
//
#include <hip/hip_runtime.h>
#include <hip/hip_bf16.h>

typedef __attribute__((ext_vector_type(8))) short short8;
typedef __attribute__((ext_vector_type(4))) short short4_t;
typedef __attribute__((ext_vector_type(8))) float f32x8;
typedef __attribute__((ext_vector_type(4))) float f32x4;
typedef __attribute__((ext_vector_type(2))) unsigned uint2v;
typedef __attribute__((ext_vector_type(4))) unsigned uint4v;

#define MFMA16(a, b, c) __builtin_amdgcn_mfma_f32_16x16x32_bf16((a), (b), (c), 0, 0, 0)

// Problem: B=2, S=2048, D=1024, H=16, Dh=64. M = B*S = 4096. Device I/O f32.
// ws layout (bf16 elem offsets):
//   Q    @ 0         [32 bh][2048 s][64 d]   (Q pre-scaled by 0.125*log2e)
//   K    @ 4194304
//   V^T  @ 8388608   [32 bh][64 d][2048 s]
//   ctx  @ 12582912  [4096][1024]
//   xbf  @ 16777216  [4096][1024]
//   wqkv @ 20971520  [3072][1024]
//   wobf @ 24117248  [1024][1024]

static __device__ __forceinline__ short f2bf(float f) {
    __hip_bfloat16 h = __float2bfloat16(f);
    return *reinterpret_cast<short*>(&h);
}

static __device__ __forceinline__ unsigned pack2bf(float lo, float hi) {
    return ((unsigned)f2bf(lo) & 0xffffu) | ((unsigned)f2bf(hi) << 16);
}

static __device__ __forceinline__ short8 u4_to_s8(uint4v u) {
    short8 s;
    __builtin_memcpy(&s, &u, 16);
    return s;
}

static __device__ __forceinline__ void g2l16(const void* g, void* l) {
    __builtin_amdgcn_global_load_lds(
        (const __attribute__((address_space(1))) void*)g,
        (__attribute__((address_space(3))) void*)l,
        16, 0, 0);
}

// ---------------- f32 -> bf16 convert pre-pass ----------------
__global__ __launch_bounds__(256) void cvt_kernel(
    const float* __restrict__ x,  const float* __restrict__ wq,
    const float* __restrict__ wk, const float* __restrict__ wv,
    const float* __restrict__ wo, __hip_bfloat16* __restrict__ ws)
{
    const size_t e = ((size_t)blockIdx.x * 256 + threadIdx.x) * 8;
    const float* src;
    __hip_bfloat16* dst;
    size_t off;
    if (e < 4194304)      { src = x;  dst = ws + 16777216; off = e; }
    else if (e < 5242880) { src = wq; dst = ws + 20971520; off = e - 4194304; }
    else if (e < 6291456) { src = wk; dst = ws + 20971520 + 1048576; off = e - 5242880; }
    else if (e < 7340032) { src = wv; dst = ws + 20971520 + 2097152; off = e - 6291456; }
    else                  { src = wo; dst = ws + 24117248; off = e - 7340032; }

    f32x8 v = *reinterpret_cast<const f32x8*>(src + off);
    short8 o;
#pragma unroll
    for (int j = 0; j < 8; ++j) o[j] = f2bf(v[j]);
    *reinterpret_cast<short8*>(reinterpret_cast<short*>(dst) + off) = o;
}

// ---------------- QKV projection GEMM (bf16, LDS-staged, BK=64) — R15 proven ----------------
__global__ __launch_bounds__(256) void qkv_gemm_kernel(
    const __hip_bfloat16* __restrict__ xbf_,
    const __hip_bfloat16* __restrict__ wqkv_,
    __hip_bfloat16* __restrict__ qkv_out)
{
    const int bid = blockIdx.x;
    const int xcd = bid & 7, kb = bid >> 3;
    const int mBlk = xcd * 4 + (kb / 24);
    const int nBlk = kb % 24;

    const int tid  = threadIdx.x;
    const int lane = tid & 63;
    const int wid  = tid >> 6;
    const int l16  = lane & 15;
    const int lhi  = lane >> 4;
    const int wr = wid >> 1, wc = wid & 1;

    const short* A = reinterpret_cast<const short*>(xbf_);
    const short* Bm = reinterpret_cast<const short*>(wqkv_);
    const int r0A = mBlk * 128, r0B = nBlk * 128;

    const int nTileBase = nBlk * 128 + wc * 64;
    const int mat = (nTileBase >> 10);            // block-uniform: 0=q 1=k 2=v
    const bool swp = (mat < 2);

    __shared__ __align__(16) short sA[128 * 64];
    __shared__ __align__(16) short sB[128 * 64];

    f32x4 acc[4][4] = {};

    for (int kk = 0; kk < 1024; kk += 64) {
#pragma unroll
        for (int it = 0; it < 4; ++it) {
            const int G = it * 256 + tid;
            const int row = G >> 3, gs = G & 7;
            const int gl = gs ^ (row & 7);
            short* lp = sA + (size_t)(it * 256 + wid * 64) * 8;
            g2l16(A + (size_t)(r0A + row) * 1024 + kk + gl * 8, lp);
        }
#pragma unroll
        for (int it = 0; it < 4; ++it) {
            const int G = it * 256 + tid;
            const int row = G >> 3, gs = G & 7;
            const int gl = gs ^ (row & 7);
            short* lp = sB + (size_t)(it * 256 + wid * 64) * 8;
            g2l16(Bm + (size_t)(r0B + row) * 1024 + kk + gl * 8, lp);
        }
        __syncthreads();

#pragma unroll
        for (int ks = 0; ks < 2; ++ks) {
            short8 a[4], b[4];
#pragma unroll
            for (int i = 0; i < 4; ++i) {
                const int row = wr * 64 + i * 16 + l16;
                const int sg = (ks * 4 + lhi) ^ (row & 7);
                a[i] = *reinterpret_cast<const short8*>(&sA[row * 64 + sg * 8]);
            }
#pragma unroll
            for (int j = 0; j < 4; ++j) {
                const int row = wc * 64 + j * 16 + l16;
                const int sg = (ks * 4 + lhi) ^ (row & 7);
                b[j] = *reinterpret_cast<const short8*>(&sB[row * 64 + sg * 8]);
            }
            if (swp) {
#pragma unroll
                for (int i = 0; i < 4; ++i)
#pragma unroll
                    for (int j = 0; j < 4; ++j)
                        acc[i][j] = MFMA16(b[j], a[i], acc[i][j]);
            } else {
#pragma unroll
                for (int i = 0; i < 4; ++i)
#pragma unroll
                    for (int j = 0; j < 4; ++j)
                        acc[i][j] = MFMA16(a[i], b[j], acc[i][j]);
            }
        }
        __syncthreads();
    }

    __hip_bfloat16* dst = qkv_out + (size_t)mat * 4194304;
    const int mBase = r0A + wr * 64;

    if (swp) {
        const float qscl = (mat == 0) ? 0.18033688f : 1.0f;  // 0.125*log2e for Q
#pragma unroll
        for (int i = 0; i < 4; ++i) {
            const int mRow = mBase + i * 16 + l16;
            const int bb = mRow >> 11, s = mRow & 2047;
#pragma unroll
            for (int j = 0; j < 4; ++j) {
                const int nCol0 = (nTileBase + j * 16 + lhi * 4) & 1023;
                const int h = nCol0 >> 6, d0 = nCol0 & 63;
                short4_t v4;
#pragma unroll
                for (int r = 0; r < 4; ++r) v4[r] = f2bf(acc[i][j][r] * qscl);
                *reinterpret_cast<short4_t*>(
                    reinterpret_cast<short*>(dst) +
                    (((size_t)(bb * 16 + h) * 2048 + s) << 6) + d0) = v4;
            }
        }
    } else {
#pragma unroll
        for (int i = 0; i < 4; ++i) {
            const int mRow0 = mBase + i * 16 + lhi * 4;
            const int bb = mRow0 >> 11, s0 = mRow0 & 2047;
#pragma unroll
            for (int j = 0; j < 4; ++j) {
                const int nCol = (nTileBase + j * 16 + l16) & 1023;
                const int h = nCol >> 6, d = nCol & 63;
                short4_t v4;
#pragma unroll
                for (int r = 0; r < 4; ++r) v4[r] = f2bf(acc[i][j][r]);
                *reinterpret_cast<short4_t*>(
                    reinterpret_cast<short*>(dst) +
                    (((size_t)(bb * 16 + h) * 64 + d) << 11) + s0) = v4;
            }
        }
    }
}

// ---------------- Flash attention (causal) — R15 structure + T4 counted vmcnt ----------------
// 512 blocks x 256 threads (4 waves). Wave = TWO 16-row q-sub-tiles (32 rows);
// block = 128 rows of ONE head. g = tg<8 ? 15-tg : tg-8 complementary pairing.
// NEW vs R15: TRIPLE-buffered K/V + counted vmcnt (T4). Per step st: issue
// stage(st+2) -> s_waitcnt vmcnt(8) (drains ONLY the 2-step-old stage, which
// has had 2 full steps to land; stages st+1, st+2 stay in flight across the
// barrier) -> raw s_barrier -> compute -> raw s_barrier (protects buffer reuse
// 2 steps later). Never vmcnt(0) in the main loop (tail guards vmcnt(4)/(0)).
// Per-wave vmcnt accounting: interior outstanding = 12 (3 stages x 4 loads);
// vmcnt(8) drains the oldest 4 = stage(st). Prologue Q-loads are among the
// drained-oldest at st=0. In-register P via the contraction-order bijection
// (R13/R14/R15 hardware-verified).
__global__ __launch_bounds__(256, 3) void attn_kernel(
    const __hip_bfloat16* __restrict__ qkv,
    __hip_bfloat16* __restrict__ ctx)
{
    const int tid  = threadIdx.x;
    const int lane = tid & 63;
    const int wid  = tid >> 6;               // 0..3
    const int l16 = lane & 15;
    const int lhi = lane >> 4;

    const int bid = blockIdx.x;              // 512 blocks
    const int xcd = bid & 7, idx = bid >> 3; // idx 0..63
    const int h4 = idx & 3, tg = idx >> 2;   // tg 0..15
    const int bh = xcd * 4 + h4;
    const int g  = (tg < 8) ? (15 - tg) : (tg - 8);  // complementary pairing
    const int q0 = g * 128 + wid * 32;       // wave's 32 rows: [q0, q0+32)
    const int sd = (q0 + 31) >> 6;           // shared diagonal step (both tiles)
    const int ns_blk = 2 * g + 2;

    const short* Q  = reinterpret_cast<const short*>(qkv) + (size_t)bh * 131072;
    const short* K  = Q + 4194304;
    const short* Vt = Q + 8388608;

    __shared__ __align__(16) short sK[3][64 * 64];
    __shared__ __align__(16) short sV[3][64 * 64];

    const int bb = bh >> 4, h = bh & 15;
    const int qrowA = q0 + l16;
    const int qrowB = q0 + 16 + l16;
    const int r7 = l16 & 7;

    short8 qfA[2], qfB[2];
    qfA[0] = *reinterpret_cast<const short8*>(Q + (size_t)qrowA * 64 + lhi * 8);
    qfA[1] = *reinterpret_cast<const short8*>(Q + (size_t)qrowA * 64 + 32 + lhi * 8);
    qfB[0] = *reinterpret_cast<const short8*>(Q + (size_t)qrowB * 64 + lhi * 8);
    qfB[1] = *reinterpret_cast<const short8*>(Q + (size_t)qrowB * 64 + 32 + lhi * 8);

    f32x4 oaccA[4] = {}, oaccB[4] = {};
    float lsumA = 0.0f, lsumB = 0.0f;

    // stage: each thread issues exactly 4 global_load_lds (16B each)
    auto stage = [&](int buf, int kv0) {
#pragma unroll
        for (int it = 0; it < 2; ++it) {
            const int G = it * 256 + tid;    // [0,512) granules of 16B
            const int row = G >> 3, gs = G & 7;
            const int gl = gs ^ (row & 7);
            g2l16(K + (size_t)(kv0 + row) * 64 + gl * 8, &sK[buf][(size_t)G * 8]);
            g2l16(Vt + (size_t)row * 2048 + kv0 + gl * 8, &sV[buf][(size_t)G * 8]);
        }
    };

    // prologue: fill pipeline 2 deep
    stage(0, 0);
    if (ns_blk > 1) stage(1, 64);

#pragma unroll 1
    for (int st = 0; st < ns_blk; ++st) {
        const int kv0 = st * 64;
        const int cur = st % 3;

        // issue stage st+2 into the buffer freed two steps ago
        if (st + 2 < ns_blk) stage((st + 2) % 3, kv0 + 128);

        // counted wait: drain ONLY stage(st); keep newer stages in flight
        if (st + 2 < ns_blk)      asm volatile("s_waitcnt vmcnt(8)" ::: "memory");
        else if (st + 1 < ns_blk) asm volatile("s_waitcnt vmcnt(4)" ::: "memory");
        else                      asm volatile("s_waitcnt vmcnt(0)" ::: "memory");
        __builtin_amdgcn_s_barrier();

        if (st <= sd) {
            // ---- QK^T swapped, shared K frags ----
            f32x4 scA[4], scB[4];
#pragma unroll
            for (int nt = 0; nt < 4; ++nt) {
                f32x4 sa = {}, sb = {};
#pragma unroll
                for (int ks = 0; ks < 2; ++ks) {
                    const int sg = (ks * 4 + lhi) ^ r7;
                    short8 kb = *reinterpret_cast<const short8*>(
                        &sK[cur][(nt * 16 + l16) * 64 + sg * 8]);
                    sa = MFMA16(kb, qfA[ks], sa);
                    sb = MFMA16(kb, qfB[ks], sb);
                }
                scA[nt] = sa;
                scB[nt] = sb;
            }

            // ---- diagonal mask (shared step) ----
            if (st == sd) {
#pragma unroll
                for (int nt = 0; nt < 4; ++nt) {
                    const int kvb = kv0 + nt * 16 + lhi * 4;
#pragma unroll
                    for (int r = 0; r < 4; ++r) {
                        if (kvb + r > qrowA) scA[nt][r] = -1.0e38f;
                        if (kvb + r > qrowB) scB[nt][r] = -1.0e38f;
                    }
                }
            }

            // ---- P = exp2 in regs; pack; defer row-sums ----
            unsigned pwA[4][2], pwB[4][2];
#pragma unroll
            for (int nt = 0; nt < 4; ++nt) {
                float a0 = exp2f(scA[nt][0]), a1 = exp2f(scA[nt][1]);
                float a2 = exp2f(scA[nt][2]), a3 = exp2f(scA[nt][3]);
                lsumA += (a0 + a1) + (a2 + a3);
                pwA[nt][0] = pack2bf(a0, a1);
                pwA[nt][1] = pack2bf(a2, a3);
                float b0 = exp2f(scB[nt][0]), b1 = exp2f(scB[nt][1]);
                float b2 = exp2f(scB[nt][2]), b3 = exp2f(scB[nt][3]);
                lsumB += (b0 + b1) + (b2 + b3);
                pwB[nt][0] = pack2bf(b0, b1);
                pwB[nt][1] = pack2bf(b2, b3);
            }

            // ---- PV: shared V reads feed both sub-tiles' MFMAs ----
#pragma unroll
            for (int ks = 0; ks < 2; ++ks) {
                uint4v ua, ub;
                ua[0] = pwA[2 * ks][0];     ub[0] = pwB[2 * ks][0];
                ua[1] = pwA[2 * ks][1];     ub[1] = pwB[2 * ks][1];
                ua[2] = pwA[2 * ks + 1][0]; ub[2] = pwB[2 * ks + 1][0];
                ua[3] = pwA[2 * ks + 1][1]; ub[3] = pwB[2 * ks + 1][1];
                short8 paA = u4_to_s8(ua);
                short8 paB = u4_to_s8(ub);
#pragma unroll
                for (int dt = 0; dt < 4; ++dt) {
                    const int row = dt * 16 + l16;
                    const int g0 = (ks * 4 + (lhi >> 1)) ^ (row & 7);
                    const int g1 = (ks * 4 + 2 + (lhi >> 1)) ^ (row & 7);
                    const int sub = (lhi & 1) * 8;
                    const char* base = reinterpret_cast<const char*>(&sV[cur][row * 64]);
                    uint2v lo  = *reinterpret_cast<const uint2v*>(base + g0 * 16 + sub);
                    uint2v hiw = *reinterpret_cast<const uint2v*>(base + g1 * 16 + sub);
                    uint4v uv;
                    uv[0] = lo[0];  uv[1] = lo[1];
                    uv[2] = hiw[0]; uv[3] = hiw[1];
                    short8 vb = u4_to_s8(uv);
                    oaccA[dt] = MFMA16(paA, vb, oaccA[dt]);
                    oaccB[dt] = MFMA16(paB, vb, oaccB[dt]);
                }
            }
        }

        // end-of-step barrier (no drain): all waves done reading buf[cur]
        // before iteration st+1 issues stage(st+3) into buf[(st+3)%3]
        __builtin_amdgcn_s_barrier();
    }

    // ---- epilogue: row-sum reductions and stores for both sub-tiles ----
    float rsA = lsumA;
    rsA += __shfl_xor(rsA, 16);
    rsA += __shfl_xor(rsA, 32);
    float rsB = lsumB;
    rsB += __shfl_xor(rsB, 16);
    rsB += __shfl_xor(rsB, 32);
    const float riA = 1.0f / rsA;
    const float riB = 1.0f / rsB;
    float rinvA[4], rinvB[4];
#pragma unroll
    for (int r = 0; r < 4; ++r) {
        rinvA[r] = __shfl(riA, lhi * 4 + r);
        rinvB[r] = __shfl(riB, lhi * 4 + r);
    }

#pragma unroll
    for (int dt = 0; dt < 4; ++dt)
#pragma unroll
        for (int r = 0; r < 4; ++r) {
            const int qA = q0 + lhi * 4 + r;
            ctx[((size_t)bb * 2048 + qA) * 1024 + h * 64 + dt * 16 + l16] =
                __float2bfloat16(oaccA[dt][r] * rinvA[r]);
            const int qB = q0 + 16 + lhi * 4 + r;
            ctx[((size_t)bb * 2048 + qB) * 1024 + h * 64 + dt * 16 + l16] =
                __float2bfloat16(oaccB[dt][r] * rinvB[r]);
        }
}

// ---------------- Output projection GEMM + bias — R8/R11 proven ----------------
__global__ __launch_bounds__(256) void out_gemm_kernel(
    const __hip_bfloat16* __restrict__ ctx,
    const __hip_bfloat16* __restrict__ wobf,
    const float* __restrict__ bo,
    float* __restrict__ out)
{
    const int bid = blockIdx.x;
    const int xcd = bid & 7, kb = bid >> 3;
    const int mBlk = xcd * 4 + (kb >> 3);
    const int nBlk = kb & 7;

    const int tid  = threadIdx.x;
    const int lane = tid & 63;
    const int wid  = tid >> 6;
    const int l16  = lane & 15;
    const int lhi  = lane >> 4;
    const int wr = wid >> 1, wc = wid & 1;

    const short* A = reinterpret_cast<const short*>(ctx);
    const short* Bm = reinterpret_cast<const short*>(wobf);
    const int r0A = mBlk * 128, r0B = nBlk * 128;

    __shared__ __align__(16) short sA[128 * 64];
    __shared__ __align__(16) short sB[128 * 64];

    f32x4 acc[4][4] = {};

    for (int kk = 0; kk < 1024; kk += 64) {
#pragma unroll
        for (int it = 0; it < 4; ++it) {
            const int G = it * 256 + tid;
            const int row = G >> 3, gs = G & 7;
            const int gl = gs ^ (row & 7);
            short* lp = sA + (size_t)(it * 256 + wid * 64) * 8;
            g2l16(A + (size_t)(r0A + row) * 1024 + kk + gl * 8, lp);
        }
#pragma unroll
        for (int it = 0; it < 4; ++it) {
            const int G = it * 256 + tid;
            const int row = G >> 3, gs = G & 7;
            const int gl = gs ^ (row & 7);
            short* lp = sB + (size_t)(it * 256 + wid * 64) * 8;
            g2l16(Bm + (size_t)(r0B + row) * 1024 + kk + gl * 8, lp);
        }
        __syncthreads();

#pragma unroll
        for (int ks = 0; ks < 2; ++ks) {
            short8 a[4], b[4];
#pragma unroll
            for (int i = 0; i < 4; ++i) {
                const int row = wr * 64 + i * 16 + l16;
                const int sg = (ks * 4 + lhi) ^ (row & 7);
                a[i] = *reinterpret_cast<const short8*>(&sA[row * 64 + sg * 8]);
            }
#pragma unroll
            for (int j = 0; j < 4; ++j) {
                const int row = wc * 64 + j * 16 + l16;
                const int sg = (ks * 4 + lhi) ^ (row & 7);
                b[j] = *reinterpret_cast<const short8*>(&sB[row * 64 + sg * 8]);
            }
#pragma unroll
            for (int i = 0; i < 4; ++i)
#pragma unroll
                for (int j = 0; j < 4; ++j)
                    acc[i][j] = MFMA16(a[i], b[j], acc[i][j]);
        }
        __syncthreads();
    }

    const int mBase = r0A + wr * 64;
    const int nBase = r0B + wc * 64;
#pragma unroll
    for (int i = 0; i < 4; ++i)
#pragma unroll
        for (int j = 0; j < 4; ++j)
#pragma unroll
            for (int r = 0; r < 4; ++r) {
                const int mRow = mBase + i * 16 + lhi * 4 + r;
                const int nCol = nBase + j * 16 + l16;
                out[(size_t)mRow * 1024 + nCol] = acc[i][j][r] + bo[nCol];
            }
}

extern "C" void kernel_launch(void* const* d_in, const int* in_sizes, int n_in,
                              void* d_out, int out_size, void* d_ws, size_t ws_size,
                              hipStream_t stream) {
    const float* x  = (const float*)d_in[0];
    const float* wq = (const float*)d_in[1];
    const float* wk = (const float*)d_in[2];
    const float* wv = (const float*)d_in[3];
    const float* wo = (const float*)d_in[4];
    const float* bo = (const float*)d_in[5];

    __hip_bfloat16* ws = (__hip_bfloat16*)d_ws;
    __hip_bfloat16* ctx  = ws + 12582912;
    __hip_bfloat16* xbf  = ws + 16777216;
    __hip_bfloat16* wqkv = ws + 20971520;
    __hip_bfloat16* wobf = ws + 24117248;
    float* out = (float*)d_out;

    cvt_kernel<<<4096, 256, 0, stream>>>(x, wq, wk, wv, wo, ws);
    qkv_gemm_kernel<<<768, 256, 0, stream>>>(xbf, wqkv, ws);
    attn_kernel<<<512, 256, 0, stream>>>(ws, ctx);
    out_gemm_kernel<<<256, 256, 0, stream>>>(ctx, wobf, bo, out);
}

// Round 21
// 116.191 us; speedup vs baseline: 1.0725x; 1.0725x over previous
//
#include <hip/hip_runtime.h>
#include <hip/hip_bf16.h>

typedef __attribute__((ext_vector_type(8))) short short8;
typedef __attribute__((ext_vector_type(4))) short short4_t;
typedef __attribute__((ext_vector_type(8))) float f32x8;
typedef __attribute__((ext_vector_type(4))) float f32x4;
typedef __attribute__((ext_vector_type(2))) unsigned uint2v;
typedef __attribute__((ext_vector_type(4))) unsigned uint4v;

#define MFMA16(a, b, c) __builtin_amdgcn_mfma_f32_16x16x32_bf16((a), (b), (c), 0, 0, 0)

// Problem: B=2, S=2048, D=1024, H=16, Dh=64. M = B*S = 4096. Device I/O f32.
// FINAL = exact R15 configuration (measured best: 116.0 us).
// ws layout (bf16 elem offsets):
//   Q    @ 0         [32 bh][2048 s][64 d]   (Q pre-scaled by 0.125*log2e)
//   K    @ 4194304
//   V^T  @ 8388608   [32 bh][64 d][2048 s]
//   ctx  @ 12582912  [4096][1024]
//   xbf  @ 16777216  [4096][1024]
//   wqkv @ 20971520  [3072][1024]
//   wobf @ 24117248  [1024][1024]

static __device__ __forceinline__ short f2bf(float f) {
    __hip_bfloat16 h = __float2bfloat16(f);
    return *reinterpret_cast<short*>(&h);
}

static __device__ __forceinline__ unsigned pack2bf(float lo, float hi) {
    return ((unsigned)f2bf(lo) & 0xffffu) | ((unsigned)f2bf(hi) << 16);
}

static __device__ __forceinline__ short8 u4_to_s8(uint4v u) {
    short8 s;
    __builtin_memcpy(&s, &u, 16);
    return s;
}

static __device__ __forceinline__ void g2l16(const void* g, void* l) {
    __builtin_amdgcn_global_load_lds(
        (const __attribute__((address_space(1))) void*)g,
        (__attribute__((address_space(3))) void*)l,
        16, 0, 0);
}

// ---------------- f32 -> bf16 convert pre-pass ----------------
__global__ __launch_bounds__(256) void cvt_kernel(
    const float* __restrict__ x,  const float* __restrict__ wq,
    const float* __restrict__ wk, const float* __restrict__ wv,
    const float* __restrict__ wo, __hip_bfloat16* __restrict__ ws)
{
    const size_t e = ((size_t)blockIdx.x * 256 + threadIdx.x) * 8;
    const float* src;
    __hip_bfloat16* dst;
    size_t off;
    if (e < 4194304)      { src = x;  dst = ws + 16777216; off = e; }
    else if (e < 5242880) { src = wq; dst = ws + 20971520; off = e - 4194304; }
    else if (e < 6291456) { src = wk; dst = ws + 20971520 + 1048576; off = e - 5242880; }
    else if (e < 7340032) { src = wv; dst = ws + 20971520 + 2097152; off = e - 6291456; }
    else                  { src = wo; dst = ws + 24117248; off = e - 7340032; }

    f32x8 v = *reinterpret_cast<const f32x8*>(src + off);
    short8 o;
#pragma unroll
    for (int j = 0; j < 8; ++j) o[j] = f2bf(v[j]);
    *reinterpret_cast<short8*>(reinterpret_cast<short*>(dst) + off) = o;
}

// ---------------- QKV projection GEMM (bf16, LDS-staged, BK=64) ----------------
// Q/K blocks use swapped MFMA operands (D: row=n, col=m) so every lane owns 4
// consecutive d -> 16 short4 stores. V keeps the transpose-store epilogue.
__global__ __launch_bounds__(256) void qkv_gemm_kernel(
    const __hip_bfloat16* __restrict__ xbf_,
    const __hip_bfloat16* __restrict__ wqkv_,
    __hip_bfloat16* __restrict__ qkv_out)
{
    const int bid = blockIdx.x;
    const int xcd = bid & 7, kb = bid >> 3;
    const int mBlk = xcd * 4 + (kb / 24);
    const int nBlk = kb % 24;

    const int tid  = threadIdx.x;
    const int lane = tid & 63;
    const int wid  = tid >> 6;
    const int l16  = lane & 15;
    const int lhi  = lane >> 4;
    const int wr = wid >> 1, wc = wid & 1;

    const short* A = reinterpret_cast<const short*>(xbf_);
    const short* Bm = reinterpret_cast<const short*>(wqkv_);
    const int r0A = mBlk * 128, r0B = nBlk * 128;

    const int nTileBase = nBlk * 128 + wc * 64;
    const int mat = (nTileBase >> 10);            // block-uniform: 0=q 1=k 2=v
    const bool swp = (mat < 2);

    __shared__ __align__(16) short sA[128 * 64];
    __shared__ __align__(16) short sB[128 * 64];

    f32x4 acc[4][4] = {};

    for (int kk = 0; kk < 1024; kk += 64) {
#pragma unroll
        for (int it = 0; it < 4; ++it) {
            const int G = it * 256 + tid;
            const int row = G >> 3, gs = G & 7;
            const int gl = gs ^ (row & 7);
            short* lp = sA + (size_t)(it * 256 + wid * 64) * 8;
            g2l16(A + (size_t)(r0A + row) * 1024 + kk + gl * 8, lp);
        }
#pragma unroll
        for (int it = 0; it < 4; ++it) {
            const int G = it * 256 + tid;
            const int row = G >> 3, gs = G & 7;
            const int gl = gs ^ (row & 7);
            short* lp = sB + (size_t)(it * 256 + wid * 64) * 8;
            g2l16(Bm + (size_t)(r0B + row) * 1024 + kk + gl * 8, lp);
        }
        __syncthreads();

#pragma unroll
        for (int ks = 0; ks < 2; ++ks) {
            short8 a[4], b[4];
#pragma unroll
            for (int i = 0; i < 4; ++i) {
                const int row = wr * 64 + i * 16 + l16;
                const int sg = (ks * 4 + lhi) ^ (row & 7);
                a[i] = *reinterpret_cast<const short8*>(&sA[row * 64 + sg * 8]);
            }
#pragma unroll
            for (int j = 0; j < 4; ++j) {
                const int row = wc * 64 + j * 16 + l16;
                const int sg = (ks * 4 + lhi) ^ (row & 7);
                b[j] = *reinterpret_cast<const short8*>(&sB[row * 64 + sg * 8]);
            }
            if (swp) {
#pragma unroll
                for (int i = 0; i < 4; ++i)
#pragma unroll
                    for (int j = 0; j < 4; ++j)
                        acc[i][j] = MFMA16(b[j], a[i], acc[i][j]);
            } else {
#pragma unroll
                for (int i = 0; i < 4; ++i)
#pragma unroll
                    for (int j = 0; j < 4; ++j)
                        acc[i][j] = MFMA16(a[i], b[j], acc[i][j]);
            }
        }
        __syncthreads();
    }

    __hip_bfloat16* dst = qkv_out + (size_t)mat * 4194304;
    const int mBase = r0A + wr * 64;

    if (swp) {
        // swapped D: row = n (lhi*4+r), col = m (l16) -> 4 consecutive d per lane
        const float qscl = (mat == 0) ? 0.18033688f : 1.0f;  // 0.125*log2e for Q
#pragma unroll
        for (int i = 0; i < 4; ++i) {
            const int mRow = mBase + i * 16 + l16;
            const int bb = mRow >> 11, s = mRow & 2047;
#pragma unroll
            for (int j = 0; j < 4; ++j) {
                const int nCol0 = (nTileBase + j * 16 + lhi * 4) & 1023;
                const int h = nCol0 >> 6, d0 = nCol0 & 63;
                short4_t v4;
#pragma unroll
                for (int r = 0; r < 4; ++r) v4[r] = f2bf(acc[i][j][r] * qscl);
                *reinterpret_cast<short4_t*>(
                    reinterpret_cast<short*>(dst) +
                    (((size_t)(bb * 16 + h) * 2048 + s) << 6) + d0) = v4;
            }
        }
    } else {
        // V transposed per head: [bh][d][s]; lane's 4 r-values = 4 consecutive s
#pragma unroll
        for (int i = 0; i < 4; ++i) {
            const int mRow0 = mBase + i * 16 + lhi * 4;
            const int bb = mRow0 >> 11, s0 = mRow0 & 2047;
#pragma unroll
            for (int j = 0; j < 4; ++j) {
                const int nCol = (nTileBase + j * 16 + l16) & 1023;
                const int h = nCol >> 6, d = nCol & 63;
                short4_t v4;
#pragma unroll
                for (int r = 0; r < 4; ++r) v4[r] = f2bf(acc[i][j][r]);
                *reinterpret_cast<short4_t*>(
                    reinterpret_cast<short*>(dst) +
                    (((size_t)(bb * 16 + h) * 64 + d) << 11) + s0) = v4;
            }
        }
    }
}

// ---------------- Flash attention (causal), 16x16 MFMA, in-reg P, 32 rows/wave ----
// 512 blocks x 256 threads (4 waves). Wave = TWO 16-row q-sub-tiles (32 rows,
// both in one 64-aligned stripe -> shared diagonal step sd); block = 128 rows of
// ONE head. g = tg<8 ? 15-tg : tg-8 -> co-resident blocks (bid, bid+256) total
// exactly 34 block-steps per CU. K-fragment and V reads are SHARED between the
// two sub-tiles. dbuf K/V staging (issue-early). In-register P via the
// contraction-order bijection (hardware-verified R13/R14/R15):
//   slot j <-> kv = ks*32 + 16*(j>>2) + 4*lhi + (j&3); B-operand = V^T row d at
//   cols ks*32+4*lhi(+16) via two ds_read_b64 (2-way bank alias = free).
__global__ __launch_bounds__(256, 3) void attn_kernel(
    const __hip_bfloat16* __restrict__ qkv,
    __hip_bfloat16* __restrict__ ctx)
{
    const int tid  = threadIdx.x;
    const int lane = tid & 63;
    const int wid  = tid >> 6;               // 0..3
    const int l16 = lane & 15;
    const int lhi = lane >> 4;

    const int bid = blockIdx.x;              // 512 blocks
    const int xcd = bid & 7, idx = bid >> 3; // idx 0..63
    const int h4 = idx & 3, tg = idx >> 2;   // tg 0..15
    const int bh = xcd * 4 + h4;
    const int g  = (tg < 8) ? (15 - tg) : (tg - 8);  // complementary pairing
    const int q0 = g * 128 + wid * 32;       // wave's 32 rows: [q0, q0+32)
    const int sd = (q0 + 31) >> 6;           // shared diagonal step (both tiles)
    const int ns_blk = 2 * g + 2;

    const short* Q  = reinterpret_cast<const short*>(qkv) + (size_t)bh * 131072;
    const short* K  = Q + 4194304;
    const short* Vt = Q + 8388608;

    __shared__ __align__(16) short sK[2][64 * 64];
    __shared__ __align__(16) short sV[2][64 * 64];

    const int bb = bh >> 4, h = bh & 15;
    const int qrowA = q0 + l16;
    const int qrowB = q0 + 16 + l16;
    const int r7 = l16 & 7;

    short8 qfA[2], qfB[2];
    qfA[0] = *reinterpret_cast<const short8*>(Q + (size_t)qrowA * 64 + lhi * 8);
    qfA[1] = *reinterpret_cast<const short8*>(Q + (size_t)qrowA * 64 + 32 + lhi * 8);
    qfB[0] = *reinterpret_cast<const short8*>(Q + (size_t)qrowB * 64 + lhi * 8);
    qfB[1] = *reinterpret_cast<const short8*>(Q + (size_t)qrowB * 64 + 32 + lhi * 8);

    f32x4 oaccA[4] = {}, oaccB[4] = {};
    float lsumA = 0.0f, lsumB = 0.0f;

    auto stage = [&](int buf, int kv0) {
#pragma unroll
        for (int it = 0; it < 2; ++it) {
            const int G = it * 256 + tid;    // [0,512) granules of 16B
            const int row = G >> 3, gs = G & 7;
            const int gl = gs ^ (row & 7);
            g2l16(K + (size_t)(kv0 + row) * 64 + gl * 8, &sK[buf][(size_t)G * 8]);
            g2l16(Vt + (size_t)row * 2048 + kv0 + gl * 8, &sV[buf][(size_t)G * 8]);
        }
    };

    stage(0, 0);
    asm volatile("s_waitcnt vmcnt(0)" ::: "memory");
    __syncthreads();

    int cur = 0;
#pragma unroll 1
    for (int st = 0; st < ns_blk; ++st) {
        const int kv0 = st * 64;
        if (st + 1 < ns_blk) stage(cur ^ 1, kv0 + 64);

        if (st <= sd) {
            // ---- QK^T swapped, shared K frags: sc*[nt][r] = S[kv][q] ----
            f32x4 scA[4], scB[4];
#pragma unroll
            for (int nt = 0; nt < 4; ++nt) {
                f32x4 sa = {}, sb = {};
#pragma unroll
                for (int ks = 0; ks < 2; ++ks) {
                    const int sg = (ks * 4 + lhi) ^ r7;
                    short8 kb = *reinterpret_cast<const short8*>(
                        &sK[cur][(nt * 16 + l16) * 64 + sg * 8]);
                    sa = MFMA16(kb, qfA[ks], sa);
                    sb = MFMA16(kb, qfB[ks], sb);
                }
                scA[nt] = sa;
                scB[nt] = sb;
            }

            // ---- diagonal mask (shared step) ----
            if (st == sd) {
#pragma unroll
                for (int nt = 0; nt < 4; ++nt) {
                    const int kvb = kv0 + nt * 16 + lhi * 4;
#pragma unroll
                    for (int r = 0; r < 4; ++r) {
                        if (kvb + r > qrowA) scA[nt][r] = -1.0e38f;
                        if (kvb + r > qrowB) scB[nt][r] = -1.0e38f;
                    }
                }
            }

            // ---- P = exp2 in regs; pack; defer row-sums ----
            unsigned pwA[4][2], pwB[4][2];
#pragma unroll
            for (int nt = 0; nt < 4; ++nt) {
                float a0 = exp2f(scA[nt][0]), a1 = exp2f(scA[nt][1]);
                float a2 = exp2f(scA[nt][2]), a3 = exp2f(scA[nt][3]);
                lsumA += (a0 + a1) + (a2 + a3);
                pwA[nt][0] = pack2bf(a0, a1);
                pwA[nt][1] = pack2bf(a2, a3);
                float b0 = exp2f(scB[nt][0]), b1 = exp2f(scB[nt][1]);
                float b2 = exp2f(scB[nt][2]), b3 = exp2f(scB[nt][3]);
                lsumB += (b0 + b1) + (b2 + b3);
                pwB[nt][0] = pack2bf(b0, b1);
                pwB[nt][1] = pack2bf(b2, b3);
            }

            // ---- PV: shared V reads feed both sub-tiles' MFMAs ----
#pragma unroll
            for (int ks = 0; ks < 2; ++ks) {
                uint4v ua, ub;
                ua[0] = pwA[2 * ks][0];     ub[0] = pwB[2 * ks][0];
                ua[1] = pwA[2 * ks][1];     ub[1] = pwB[2 * ks][1];
                ua[2] = pwA[2 * ks + 1][0]; ub[2] = pwB[2 * ks + 1][0];
                ua[3] = pwA[2 * ks + 1][1]; ub[3] = pwB[2 * ks + 1][1];
                short8 paA = u4_to_s8(ua);
                short8 paB = u4_to_s8(ub);
#pragma unroll
                for (int dt = 0; dt < 4; ++dt) {
                    const int row = dt * 16 + l16;
                    const int g0 = (ks * 4 + (lhi >> 1)) ^ (row & 7);
                    const int g1 = (ks * 4 + 2 + (lhi >> 1)) ^ (row & 7);
                    const int sub = (lhi & 1) * 8;
                    const char* base = reinterpret_cast<const char*>(&sV[cur][row * 64]);
                    uint2v lo  = *reinterpret_cast<const uint2v*>(base + g0 * 16 + sub);
                    uint2v hiw = *reinterpret_cast<const uint2v*>(base + g1 * 16 + sub);
                    uint4v uv;
                    uv[0] = lo[0];  uv[1] = lo[1];
                    uv[2] = hiw[0]; uv[3] = hiw[1];
                    short8 vb = u4_to_s8(uv);
                    oaccA[dt] = MFMA16(paA, vb, oaccA[dt]);
                    oaccB[dt] = MFMA16(paB, vb, oaccB[dt]);
                }
            }
        }

        asm volatile("s_waitcnt vmcnt(0)" ::: "memory");
        __syncthreads();
        cur ^= 1;
    }

    // ---- epilogue: row-sum reductions and stores for both sub-tiles ----
    float rsA = lsumA;
    rsA += __shfl_xor(rsA, 16);
    rsA += __shfl_xor(rsA, 32);
    float rsB = lsumB;
    rsB += __shfl_xor(rsB, 16);
    rsB += __shfl_xor(rsB, 32);
    const float riA = 1.0f / rsA;
    const float riB = 1.0f / rsB;
    float rinvA[4], rinvB[4];
#pragma unroll
    for (int r = 0; r < 4; ++r) {
        rinvA[r] = __shfl(riA, lhi * 4 + r);
        rinvB[r] = __shfl(riB, lhi * 4 + r);
    }

#pragma unroll
    for (int dt = 0; dt < 4; ++dt)
#pragma unroll
        for (int r = 0; r < 4; ++r) {
            const int qA = q0 + lhi * 4 + r;
            ctx[((size_t)bb * 2048 + qA) * 1024 + h * 64 + dt * 16 + l16] =
                __float2bfloat16(oaccA[dt][r] * rinvA[r]);
            const int qB = q0 + 16 + lhi * 4 + r;
            ctx[((size_t)bb * 2048 + qB) * 1024 + h * 64 + dt * 16 + l16] =
                __float2bfloat16(oaccB[dt][r] * rinvB[r]);
        }
}

// ---------------- Output projection GEMM + bias ----------------
__global__ __launch_bounds__(256) void out_gemm_kernel(
    const __hip_bfloat16* __restrict__ ctx,
    const __hip_bfloat16* __restrict__ wobf,
    const float* __restrict__ bo,
    float* __restrict__ out)
{
    const int bid = blockIdx.x;
    const int xcd = bid & 7, kb = bid >> 3;
    const int mBlk = xcd * 4 + (kb >> 3);
    const int nBlk = kb & 7;

    const int tid  = threadIdx.x;
    const int lane = tid & 63;
    const int wid  = tid >> 6;
    const int l16  = lane & 15;
    const int lhi  = lane >> 4;
    const int wr = wid >> 1, wc = wid & 1;

    const short* A = reinterpret_cast<const short*>(ctx);
    const short* Bm = reinterpret_cast<const short*>(wobf);
    const int r0A = mBlk * 128, r0B = nBlk * 128;

    __shared__ __align__(16) short sA[128 * 64];
    __shared__ __align__(16) short sB[128 * 64];

    f32x4 acc[4][4] = {};

    for (int kk = 0; kk < 1024; kk += 64) {
#pragma unroll
        for (int it = 0; it < 4; ++it) {
            const int G = it * 256 + tid;
            const int row = G >> 3, gs = G & 7;
            const int gl = gs ^ (row & 7);
            short* lp = sA + (size_t)(it * 256 + wid * 64) * 8;
            g2l16(A + (size_t)(r0A + row) * 1024 + kk + gl * 8, lp);
        }
#pragma unroll
        for (int it = 0; it < 4; ++it) {
            const int G = it * 256 + tid;
            const int row = G >> 3, gs = G & 7;
            const int gl = gs ^ (row & 7);
            short* lp = sB + (size_t)(it * 256 + wid * 64) * 8;
            g2l16(Bm + (size_t)(r0B + row) * 1024 + kk + gl * 8, lp);
        }
        __syncthreads();

#pragma unroll
        for (int ks = 0; ks < 2; ++ks) {
            short8 a[4], b[4];
#pragma unroll
            for (int i = 0; i < 4; ++i) {
                const int row = wr * 64 + i * 16 + l16;
                const int sg = (ks * 4 + lhi) ^ (row & 7);
                a[i] = *reinterpret_cast<const short8*>(&sA[row * 64 + sg * 8]);
            }
#pragma unroll
            for (int j = 0; j < 4; ++j) {
                const int row = wc * 64 + j * 16 + l16;
                const int sg = (ks * 4 + lhi) ^ (row & 7);
                b[j] = *reinterpret_cast<const short8*>(&sB[row * 64 + sg * 8]);
            }
#pragma unroll
            for (int i = 0; i < 4; ++i)
#pragma unroll
                for (int j = 0; j < 4; ++j)
                    acc[i][j] = MFMA16(a[i], b[j], acc[i][j]);
        }
        __syncthreads();
    }

    const int mBase = r0A + wr * 64;
    const int nBase = r0B + wc * 64;
#pragma unroll
    for (int i = 0; i < 4; ++i)
#pragma unroll
        for (int j = 0; j < 4; ++j)
#pragma unroll
            for (int r = 0; r < 4; ++r) {
                const int mRow = mBase + i * 16 + lhi * 4 + r;
                const int nCol = nBase + j * 16 + l16;
                out[(size_t)mRow * 1024 + nCol] = acc[i][j][r] + bo[nCol];
            }
}

extern "C" void kernel_launch(void* const* d_in, const int* in_sizes, int n_in,
                              void* d_out, int out_size, void* d_ws, size_t ws_size,
                              hipStream_t stream) {
    const float* x  = (const float*)d_in[0];
    const float* wq = (const float*)d_in[1];
    const float* wk = (const float*)d_in[2];
    const float* wv = (const float*)d_in[3];
    const float* wo = (const float*)d_in[4];
    const float* bo = (const float*)d_in[5];

    __hip_bfloat16* ws = (__hip_bfloat16*)d_ws;
    __hip_bfloat16* ctx  = ws + 12582912;
    __hip_bfloat16* xbf  = ws + 16777216;
    __hip_bfloat16* wqkv = ws + 20971520;
    __hip_bfloat16* wobf = ws + 24117248;
    float* out = (float*)d_out;

    cvt_kernel<<<4096, 256, 0, stream>>>(x, wq, wk, wv, wo, ws);
    qkv_gemm_kernel<<<768, 256, 0, stream>>>(xbf, wqkv, ws);
    attn_kernel<<<512, 256, 0, stream>>>(ws, ctx);
    out_gemm_kernel<<<256, 256, 0, stream>>>(ctx, wobf, bo, out);
}

// Round 22
// 110.844 us; speedup vs baseline: 1.1243x; 1.0482x over previous
//
#include <hip/hip_runtime.h>
#include <hip/hip_bf16.h>

typedef __attribute__((ext_vector_type(8))) short short8;
typedef __attribute__((ext_vector_type(4))) short short4_t;
typedef __attribute__((ext_vector_type(8))) float f32x8;
typedef __attribute__((ext_vector_type(4))) float f32x4;
typedef __attribute__((ext_vector_type(2))) unsigned uint2v;
typedef __attribute__((ext_vector_type(4))) unsigned uint4v;

#define MFMA16(a, b, c) __builtin_amdgcn_mfma_f32_16x16x32_bf16((a), (b), (c), 0, 0, 0)

// Problem: B=2, S=2048, D=1024, H=16, Dh=64. M = B*S = 4096. Device I/O f32.
// R15 configuration (measured best: 116.0 us) + out_gemm at 64x128 tiles
// (512 blocks = 2 blocks/CU, was 1/CU -> exposed barrier drains).
// ws layout (bf16 elem offsets):
//   Q    @ 0         [32 bh][2048 s][64 d]   (Q pre-scaled by 0.125*log2e)
//   K    @ 4194304
//   V^T  @ 8388608   [32 bh][64 d][2048 s]
//   ctx  @ 12582912  [4096][1024]
//   xbf  @ 16777216  [4096][1024]
//   wqkv @ 20971520  [3072][1024]
//   wobf @ 24117248  [1024][1024]

static __device__ __forceinline__ short f2bf(float f) {
    __hip_bfloat16 h = __float2bfloat16(f);
    return *reinterpret_cast<short*>(&h);
}

static __device__ __forceinline__ unsigned pack2bf(float lo, float hi) {
    return ((unsigned)f2bf(lo) & 0xffffu) | ((unsigned)f2bf(hi) << 16);
}

static __device__ __forceinline__ short8 u4_to_s8(uint4v u) {
    short8 s;
    __builtin_memcpy(&s, &u, 16);
    return s;
}

static __device__ __forceinline__ void g2l16(const void* g, void* l) {
    __builtin_amdgcn_global_load_lds(
        (const __attribute__((address_space(1))) void*)g,
        (__attribute__((address_space(3))) void*)l,
        16, 0, 0);
}

// ---------------- f32 -> bf16 convert pre-pass ----------------
__global__ __launch_bounds__(256) void cvt_kernel(
    const float* __restrict__ x,  const float* __restrict__ wq,
    const float* __restrict__ wk, const float* __restrict__ wv,
    const float* __restrict__ wo, __hip_bfloat16* __restrict__ ws)
{
    const size_t e = ((size_t)blockIdx.x * 256 + threadIdx.x) * 8;
    const float* src;
    __hip_bfloat16* dst;
    size_t off;
    if (e < 4194304)      { src = x;  dst = ws + 16777216; off = e; }
    else if (e < 5242880) { src = wq; dst = ws + 20971520; off = e - 4194304; }
    else if (e < 6291456) { src = wk; dst = ws + 20971520 + 1048576; off = e - 5242880; }
    else if (e < 7340032) { src = wv; dst = ws + 20971520 + 2097152; off = e - 6291456; }
    else                  { src = wo; dst = ws + 24117248; off = e - 7340032; }

    f32x8 v = *reinterpret_cast<const f32x8*>(src + off);
    short8 o;
#pragma unroll
    for (int j = 0; j < 8; ++j) o[j] = f2bf(v[j]);
    *reinterpret_cast<short8*>(reinterpret_cast<short*>(dst) + off) = o;
}

// ---------------- QKV projection GEMM (bf16, LDS-staged, BK=64) — R15 proven ----------------
__global__ __launch_bounds__(256) void qkv_gemm_kernel(
    const __hip_bfloat16* __restrict__ xbf_,
    const __hip_bfloat16* __restrict__ wqkv_,
    __hip_bfloat16* __restrict__ qkv_out)
{
    const int bid = blockIdx.x;
    const int xcd = bid & 7, kb = bid >> 3;
    const int mBlk = xcd * 4 + (kb / 24);
    const int nBlk = kb % 24;

    const int tid  = threadIdx.x;
    const int lane = tid & 63;
    const int wid  = tid >> 6;
    const int l16  = lane & 15;
    const int lhi  = lane >> 4;
    const int wr = wid >> 1, wc = wid & 1;

    const short* A = reinterpret_cast<const short*>(xbf_);
    const short* Bm = reinterpret_cast<const short*>(wqkv_);
    const int r0A = mBlk * 128, r0B = nBlk * 128;

    const int nTileBase = nBlk * 128 + wc * 64;
    const int mat = (nTileBase >> 10);            // block-uniform: 0=q 1=k 2=v
    const bool swp = (mat < 2);

    __shared__ __align__(16) short sA[128 * 64];
    __shared__ __align__(16) short sB[128 * 64];

    f32x4 acc[4][4] = {};

    for (int kk = 0; kk < 1024; kk += 64) {
#pragma unroll
        for (int it = 0; it < 4; ++it) {
            const int G = it * 256 + tid;
            const int row = G >> 3, gs = G & 7;
            const int gl = gs ^ (row & 7);
            short* lp = sA + (size_t)(it * 256 + wid * 64) * 8;
            g2l16(A + (size_t)(r0A + row) * 1024 + kk + gl * 8, lp);
        }
#pragma unroll
        for (int it = 0; it < 4; ++it) {
            const int G = it * 256 + tid;
            const int row = G >> 3, gs = G & 7;
            const int gl = gs ^ (row & 7);
            short* lp = sB + (size_t)(it * 256 + wid * 64) * 8;
            g2l16(Bm + (size_t)(r0B + row) * 1024 + kk + gl * 8, lp);
        }
        __syncthreads();

#pragma unroll
        for (int ks = 0; ks < 2; ++ks) {
            short8 a[4], b[4];
#pragma unroll
            for (int i = 0; i < 4; ++i) {
                const int row = wr * 64 + i * 16 + l16;
                const int sg = (ks * 4 + lhi) ^ (row & 7);
                a[i] = *reinterpret_cast<const short8*>(&sA[row * 64 + sg * 8]);
            }
#pragma unroll
            for (int j = 0; j < 4; ++j) {
                const int row = wc * 64 + j * 16 + l16;
                const int sg = (ks * 4 + lhi) ^ (row & 7);
                b[j] = *reinterpret_cast<const short8*>(&sB[row * 64 + sg * 8]);
            }
            if (swp) {
#pragma unroll
                for (int i = 0; i < 4; ++i)
#pragma unroll
                    for (int j = 0; j < 4; ++j)
                        acc[i][j] = MFMA16(b[j], a[i], acc[i][j]);
            } else {
#pragma unroll
                for (int i = 0; i < 4; ++i)
#pragma unroll
                    for (int j = 0; j < 4; ++j)
                        acc[i][j] = MFMA16(a[i], b[j], acc[i][j]);
            }
        }
        __syncthreads();
    }

    __hip_bfloat16* dst = qkv_out + (size_t)mat * 4194304;
    const int mBase = r0A + wr * 64;

    if (swp) {
        // swapped D: row = n (lhi*4+r), col = m (l16) -> 4 consecutive d per lane
        const float qscl = (mat == 0) ? 0.18033688f : 1.0f;  // 0.125*log2e for Q
#pragma unroll
        for (int i = 0; i < 4; ++i) {
            const int mRow = mBase + i * 16 + l16;
            const int bb = mRow >> 11, s = mRow & 2047;
#pragma unroll
            for (int j = 0; j < 4; ++j) {
                const int nCol0 = (nTileBase + j * 16 + lhi * 4) & 1023;
                const int h = nCol0 >> 6, d0 = nCol0 & 63;
                short4_t v4;
#pragma unroll
                for (int r = 0; r < 4; ++r) v4[r] = f2bf(acc[i][j][r] * qscl);
                *reinterpret_cast<short4_t*>(
                    reinterpret_cast<short*>(dst) +
                    (((size_t)(bb * 16 + h) * 2048 + s) << 6) + d0) = v4;
            }
        }
    } else {
        // V transposed per head: [bh][d][s]; lane's 4 r-values = 4 consecutive s
#pragma unroll
        for (int i = 0; i < 4; ++i) {
            const int mRow0 = mBase + i * 16 + lhi * 4;
            const int bb = mRow0 >> 11, s0 = mRow0 & 2047;
#pragma unroll
            for (int j = 0; j < 4; ++j) {
                const int nCol = (nTileBase + j * 16 + l16) & 1023;
                const int h = nCol >> 6, d = nCol & 63;
                short4_t v4;
#pragma unroll
                for (int r = 0; r < 4; ++r) v4[r] = f2bf(acc[i][j][r]);
                *reinterpret_cast<short4_t*>(
                    reinterpret_cast<short*>(dst) +
                    (((size_t)(bb * 16 + h) * 64 + d) << 11) + s0) = v4;
            }
        }
    }
}

// ---------------- Flash attention (causal) — exact R15 (measured best) ----------------
__global__ __launch_bounds__(256, 3) void attn_kernel(
    const __hip_bfloat16* __restrict__ qkv,
    __hip_bfloat16* __restrict__ ctx)
{
    const int tid  = threadIdx.x;
    const int lane = tid & 63;
    const int wid  = tid >> 6;               // 0..3
    const int l16 = lane & 15;
    const int lhi = lane >> 4;

    const int bid = blockIdx.x;              // 512 blocks
    const int xcd = bid & 7, idx = bid >> 3; // idx 0..63
    const int h4 = idx & 3, tg = idx >> 2;   // tg 0..15
    const int bh = xcd * 4 + h4;
    const int g  = (tg < 8) ? (15 - tg) : (tg - 8);  // complementary pairing
    const int q0 = g * 128 + wid * 32;       // wave's 32 rows: [q0, q0+32)
    const int sd = (q0 + 31) >> 6;           // shared diagonal step (both tiles)
    const int ns_blk = 2 * g + 2;

    const short* Q  = reinterpret_cast<const short*>(qkv) + (size_t)bh * 131072;
    const short* K  = Q + 4194304;
    const short* Vt = Q + 8388608;

    __shared__ __align__(16) short sK[2][64 * 64];
    __shared__ __align__(16) short sV[2][64 * 64];

    const int bb = bh >> 4, h = bh & 15;
    const int qrowA = q0 + l16;
    const int qrowB = q0 + 16 + l16;
    const int r7 = l16 & 7;

    short8 qfA[2], qfB[2];
    qfA[0] = *reinterpret_cast<const short8*>(Q + (size_t)qrowA * 64 + lhi * 8);
    qfA[1] = *reinterpret_cast<const short8*>(Q + (size_t)qrowA * 64 + 32 + lhi * 8);
    qfB[0] = *reinterpret_cast<const short8*>(Q + (size_t)qrowB * 64 + lhi * 8);
    qfB[1] = *reinterpret_cast<const short8*>(Q + (size_t)qrowB * 64 + 32 + lhi * 8);

    f32x4 oaccA[4] = {}, oaccB[4] = {};
    float lsumA = 0.0f, lsumB = 0.0f;

    auto stage = [&](int buf, int kv0) {
#pragma unroll
        for (int it = 0; it < 2; ++it) {
            const int G = it * 256 + tid;    // [0,512) granules of 16B
            const int row = G >> 3, gs = G & 7;
            const int gl = gs ^ (row & 7);
            g2l16(K + (size_t)(kv0 + row) * 64 + gl * 8, &sK[buf][(size_t)G * 8]);
            g2l16(Vt + (size_t)row * 2048 + kv0 + gl * 8, &sV[buf][(size_t)G * 8]);
        }
    };

    stage(0, 0);
    asm volatile("s_waitcnt vmcnt(0)" ::: "memory");
    __syncthreads();

    int cur = 0;
#pragma unroll 1
    for (int st = 0; st < ns_blk; ++st) {
        const int kv0 = st * 64;
        if (st + 1 < ns_blk) stage(cur ^ 1, kv0 + 64);

        if (st <= sd) {
            // ---- QK^T swapped, shared K frags: sc*[nt][r] = S[kv][q] ----
            f32x4 scA[4], scB[4];
#pragma unroll
            for (int nt = 0; nt < 4; ++nt) {
                f32x4 sa = {}, sb = {};
#pragma unroll
                for (int ks = 0; ks < 2; ++ks) {
                    const int sg = (ks * 4 + lhi) ^ r7;
                    short8 kb = *reinterpret_cast<const short8*>(
                        &sK[cur][(nt * 16 + l16) * 64 + sg * 8]);
                    sa = MFMA16(kb, qfA[ks], sa);
                    sb = MFMA16(kb, qfB[ks], sb);
                }
                scA[nt] = sa;
                scB[nt] = sb;
            }

            // ---- diagonal mask (shared step) ----
            if (st == sd) {
#pragma unroll
                for (int nt = 0; nt < 4; ++nt) {
                    const int kvb = kv0 + nt * 16 + lhi * 4;
#pragma unroll
                    for (int r = 0; r < 4; ++r) {
                        if (kvb + r > qrowA) scA[nt][r] = -1.0e38f;
                        if (kvb + r > qrowB) scB[nt][r] = -1.0e38f;
                    }
                }
            }

            // ---- P = exp2 in regs; pack; defer row-sums ----
            unsigned pwA[4][2], pwB[4][2];
#pragma unroll
            for (int nt = 0; nt < 4; ++nt) {
                float a0 = exp2f(scA[nt][0]), a1 = exp2f(scA[nt][1]);
                float a2 = exp2f(scA[nt][2]), a3 = exp2f(scA[nt][3]);
                lsumA += (a0 + a1) + (a2 + a3);
                pwA[nt][0] = pack2bf(a0, a1);
                pwA[nt][1] = pack2bf(a2, a3);
                float b0 = exp2f(scB[nt][0]), b1 = exp2f(scB[nt][1]);
                float b2 = exp2f(scB[nt][2]), b3 = exp2f(scB[nt][3]);
                lsumB += (b0 + b1) + (b2 + b3);
                pwB[nt][0] = pack2bf(b0, b1);
                pwB[nt][1] = pack2bf(b2, b3);
            }

            // ---- PV: shared V reads feed both sub-tiles' MFMAs ----
#pragma unroll
            for (int ks = 0; ks < 2; ++ks) {
                uint4v ua, ub;
                ua[0] = pwA[2 * ks][0];     ub[0] = pwB[2 * ks][0];
                ua[1] = pwA[2 * ks][1];     ub[1] = pwB[2 * ks][1];
                ua[2] = pwA[2 * ks + 1][0]; ub[2] = pwB[2 * ks + 1][0];
                ua[3] = pwA[2 * ks + 1][1]; ub[3] = pwB[2 * ks + 1][1];
                short8 paA = u4_to_s8(ua);
                short8 paB = u4_to_s8(ub);
#pragma unroll
                for (int dt = 0; dt < 4; ++dt) {
                    const int row = dt * 16 + l16;
                    const int g0 = (ks * 4 + (lhi >> 1)) ^ (row & 7);
                    const int g1 = (ks * 4 + 2 + (lhi >> 1)) ^ (row & 7);
                    const int sub = (lhi & 1) * 8;
                    const char* base = reinterpret_cast<const char*>(&sV[cur][row * 64]);
                    uint2v lo  = *reinterpret_cast<const uint2v*>(base + g0 * 16 + sub);
                    uint2v hiw = *reinterpret_cast<const uint2v*>(base + g1 * 16 + sub);
                    uint4v uv;
                    uv[0] = lo[0];  uv[1] = lo[1];
                    uv[2] = hiw[0]; uv[3] = hiw[1];
                    short8 vb = u4_to_s8(uv);
                    oaccA[dt] = MFMA16(paA, vb, oaccA[dt]);
                    oaccB[dt] = MFMA16(paB, vb, oaccB[dt]);
                }
            }
        }

        asm volatile("s_waitcnt vmcnt(0)" ::: "memory");
        __syncthreads();
        cur ^= 1;
    }

    // ---- epilogue: row-sum reductions and stores for both sub-tiles ----
    float rsA = lsumA;
    rsA += __shfl_xor(rsA, 16);
    rsA += __shfl_xor(rsA, 32);
    float rsB = lsumB;
    rsB += __shfl_xor(rsB, 16);
    rsB += __shfl_xor(rsB, 32);
    const float riA = 1.0f / rsA;
    const float riB = 1.0f / rsB;
    float rinvA[4], rinvB[4];
#pragma unroll
    for (int r = 0; r < 4; ++r) {
        rinvA[r] = __shfl(riA, lhi * 4 + r);
        rinvB[r] = __shfl(riB, lhi * 4 + r);
    }

#pragma unroll
    for (int dt = 0; dt < 4; ++dt)
#pragma unroll
        for (int r = 0; r < 4; ++r) {
            const int qA = q0 + lhi * 4 + r;
            ctx[((size_t)bb * 2048 + qA) * 1024 + h * 64 + dt * 16 + l16] =
                __float2bfloat16(oaccA[dt][r] * rinvA[r]);
            const int qB = q0 + 16 + lhi * 4 + r;
            ctx[((size_t)bb * 2048 + qB) * 1024 + h * 64 + dt * 16 + l16] =
                __float2bfloat16(oaccB[dt][r] * rinvB[r]);
        }
}

// ---------------- Output projection GEMM + bias (64x128 tiles, 2 blocks/CU) ----------------
// 512 blocks x 256 threads. Block = 64 M-rows x 128 N-cols; wave (wr,wc) owns a
// 32x64 sub-tile (acc[2][4]). Same BK=64 loop + 0-conflict XOR swizzle as the
// proven 128x128 version; doubling blocks/CU (1 -> 2) lets co-resident blocks
// hide each other's per-step vmcnt(0)+barrier drains (R10 vs R15 mechanism).
__global__ __launch_bounds__(256) void out_gemm_kernel(
    const __hip_bfloat16* __restrict__ ctx,
    const __hip_bfloat16* __restrict__ wobf,
    const float* __restrict__ bo,
    float* __restrict__ out)
{
    const int bid = blockIdx.x;
    const int xcd = bid & 7, kb = bid >> 3;       // kb in [0,64)
    const int mBlk = xcd * 8 + (kb >> 3);         // [0,64): 64-row tiles
    const int nBlk = kb & 7;                      // [0,8): 128-col tiles

    const int tid  = threadIdx.x;
    const int lane = tid & 63;
    const int wid  = tid >> 6;
    const int l16  = lane & 15;
    const int lhi  = lane >> 4;
    const int wr = wid >> 1, wc = wid & 1;

    const short* A = reinterpret_cast<const short*>(ctx);
    const short* Bm = reinterpret_cast<const short*>(wobf);
    const int r0A = mBlk * 64, r0B = nBlk * 128;

    __shared__ __align__(16) short sA[64 * 64];
    __shared__ __align__(16) short sB[128 * 64];

    f32x4 acc[2][4] = {};

    for (int kk = 0; kk < 1024; kk += 64) {
        // A: 64x64 tile = 512 granules; 2 per thread
#pragma unroll
        for (int it = 0; it < 2; ++it) {
            const int G = it * 256 + tid;
            const int row = G >> 3, gs = G & 7;
            const int gl = gs ^ (row & 7);
            g2l16(A + (size_t)(r0A + row) * 1024 + kk + gl * 8, &sA[(size_t)G * 8]);
        }
        // B: 128x64 tile = 1024 granules; 4 per thread
#pragma unroll
        for (int it = 0; it < 4; ++it) {
            const int G = it * 256 + tid;
            const int row = G >> 3, gs = G & 7;
            const int gl = gs ^ (row & 7);
            g2l16(Bm + (size_t)(r0B + row) * 1024 + kk + gl * 8, &sB[(size_t)G * 8]);
        }
        __syncthreads();

#pragma unroll
        for (int ks = 0; ks < 2; ++ks) {
            short8 a[2], b[4];
#pragma unroll
            for (int i = 0; i < 2; ++i) {
                const int row = wr * 32 + i * 16 + l16;
                const int sg = (ks * 4 + lhi) ^ (row & 7);
                a[i] = *reinterpret_cast<const short8*>(&sA[row * 64 + sg * 8]);
            }
#pragma unroll
            for (int j = 0; j < 4; ++j) {
                const int row = wc * 64 + j * 16 + l16;
                const int sg = (ks * 4 + lhi) ^ (row & 7);
                b[j] = *reinterpret_cast<const short8*>(&sB[row * 64 + sg * 8]);
            }
#pragma unroll
            for (int i = 0; i < 2; ++i)
#pragma unroll
                for (int j = 0; j < 4; ++j)
                    acc[i][j] = MFMA16(a[i], b[j], acc[i][j]);
        }
        __syncthreads();
    }

    const int mBase = r0A + wr * 32;
    const int nBase = r0B + wc * 64;
#pragma unroll
    for (int i = 0; i < 2; ++i)
#pragma unroll
        for (int j = 0; j < 4; ++j)
#pragma unroll
            for (int r = 0; r < 4; ++r) {
                const int mRow = mBase + i * 16 + lhi * 4 + r;
                const int nCol = nBase + j * 16 + l16;
                out[(size_t)mRow * 1024 + nCol] = acc[i][j][r] + bo[nCol];
            }
}

extern "C" void kernel_launch(void* const* d_in, const int* in_sizes, int n_in,
                              void* d_out, int out_size, void* d_ws, size_t ws_size,
                              hipStream_t stream) {
    const float* x  = (const float*)d_in[0];
    const float* wq = (const float*)d_in[1];
    const float* wk = (const float*)d_in[2];
    const float* wv = (const float*)d_in[3];
    const float* wo = (const float*)d_in[4];
    const float* bo = (const float*)d_in[5];

    __hip_bfloat16* ws = (__hip_bfloat16*)d_ws;
    __hip_bfloat16* ctx  = ws + 12582912;
    __hip_bfloat16* xbf  = ws + 16777216;
    __hip_bfloat16* wqkv = ws + 20971520;
    __hip_bfloat16* wobf = ws + 24117248;
    float* out = (float*)d_out;

    cvt_kernel<<<4096, 256, 0, stream>>>(x, wq, wk, wv, wo, ws);
    qkv_gemm_kernel<<<768, 256, 0, stream>>>(xbf, wqkv, ws);
    attn_kernel<<<512, 256, 0, stream>>>(ws, ctx);
    out_gemm_kernel<<<512, 256, 0, stream>>>(ctx, wobf, bo, out);
}

// Round 23
// 106.760 us; speedup vs baseline: 1.1673x; 1.0383x over previous
//
#include <hip/hip_runtime.h>
#include <hip/hip_bf16.h>

typedef __attribute__((ext_vector_type(8))) short short8;
typedef __attribute__((ext_vector_type(4))) short short4_t;
typedef __attribute__((ext_vector_type(8))) float f32x8;
typedef __attribute__((ext_vector_type(4))) float f32x4;
typedef __attribute__((ext_vector_type(2))) unsigned uint2v;
typedef __attribute__((ext_vector_type(4))) unsigned uint4v;

#define MFMA16(a, b, c) __builtin_amdgcn_mfma_f32_16x16x32_bf16((a), (b), (c), 0, 0, 0)

// Problem: B=2, S=2048, D=1024, H=16, Dh=64. M = B*S = 4096. Device I/O f32.
// R22 best (110.8 us) + qkv_gemm retiled 128x128 -> 64x128 (3 -> 6 blocks/CU,
// same drain-overlap mechanism that gained out_gemm ~38% in R22).
// ws layout (bf16 elem offsets):
//   Q    @ 0         [32 bh][2048 s][64 d]   (Q pre-scaled by 0.125*log2e)
//   K    @ 4194304
//   V^T  @ 8388608   [32 bh][64 d][2048 s]
//   ctx  @ 12582912  [4096][1024]
//   xbf  @ 16777216  [4096][1024]
//   wqkv @ 20971520  [3072][1024]
//   wobf @ 24117248  [1024][1024]

static __device__ __forceinline__ short f2bf(float f) {
    __hip_bfloat16 h = __float2bfloat16(f);
    return *reinterpret_cast<short*>(&h);
}

static __device__ __forceinline__ unsigned pack2bf(float lo, float hi) {
    return ((unsigned)f2bf(lo) & 0xffffu) | ((unsigned)f2bf(hi) << 16);
}

static __device__ __forceinline__ short8 u4_to_s8(uint4v u) {
    short8 s;
    __builtin_memcpy(&s, &u, 16);
    return s;
}

static __device__ __forceinline__ void g2l16(const void* g, void* l) {
    __builtin_amdgcn_global_load_lds(
        (const __attribute__((address_space(1))) void*)g,
        (__attribute__((address_space(3))) void*)l,
        16, 0, 0);
}

// ---------------- f32 -> bf16 convert pre-pass ----------------
__global__ __launch_bounds__(256) void cvt_kernel(
    const float* __restrict__ x,  const float* __restrict__ wq,
    const float* __restrict__ wk, const float* __restrict__ wv,
    const float* __restrict__ wo, __hip_bfloat16* __restrict__ ws)
{
    const size_t e = ((size_t)blockIdx.x * 256 + threadIdx.x) * 8;
    const float* src;
    __hip_bfloat16* dst;
    size_t off;
    if (e < 4194304)      { src = x;  dst = ws + 16777216; off = e; }
    else if (e < 5242880) { src = wq; dst = ws + 20971520; off = e - 4194304; }
    else if (e < 6291456) { src = wk; dst = ws + 20971520 + 1048576; off = e - 5242880; }
    else if (e < 7340032) { src = wv; dst = ws + 20971520 + 2097152; off = e - 6291456; }
    else                  { src = wo; dst = ws + 24117248; off = e - 7340032; }

    f32x8 v = *reinterpret_cast<const f32x8*>(src + off);
    short8 o;
#pragma unroll
    for (int j = 0; j < 8; ++j) o[j] = f2bf(v[j]);
    *reinterpret_cast<short8*>(reinterpret_cast<short*>(dst) + off) = o;
}

// ---------------- QKV projection GEMM (bf16, 64x128 tiles, 6 blocks/CU) ----------------
// 1536 blocks x 256 threads. Block = 64 M-rows x 128 N-cols; wave (wr,wc) owns
// a 32x64 sub-tile (acc[2][4]). Q/K blocks use swapped MFMA operands so each
// lane owns 4 consecutive d -> short4 stores. V keeps the transpose epilogue.
__global__ __launch_bounds__(256) void qkv_gemm_kernel(
    const __hip_bfloat16* __restrict__ xbf_,
    const __hip_bfloat16* __restrict__ wqkv_,
    __hip_bfloat16* __restrict__ qkv_out)
{
    const int bid = blockIdx.x;
    const int xcd = bid & 7, kb = bid >> 3;       // kb in [0,192)
    const int mBlk = xcd * 8 + (kb / 24);         // [0,64): 64-row tiles
    const int nBlk = kb % 24;                     // [0,24): 128-col tiles

    const int tid  = threadIdx.x;
    const int lane = tid & 63;
    const int wid  = tid >> 6;
    const int l16  = lane & 15;
    const int lhi  = lane >> 4;
    const int wr = wid >> 1, wc = wid & 1;

    const short* A = reinterpret_cast<const short*>(xbf_);
    const short* Bm = reinterpret_cast<const short*>(wqkv_);
    const int r0A = mBlk * 64, r0B = nBlk * 128;

    const int nTileBase = nBlk * 128 + wc * 64;
    const int mat = (nTileBase >> 10);            // block-uniform: 0=q 1=k 2=v
    const bool swp = (mat < 2);

    __shared__ __align__(16) short sA[64 * 64];
    __shared__ __align__(16) short sB[128 * 64];

    f32x4 acc[2][4] = {};

    for (int kk = 0; kk < 1024; kk += 64) {
        // A: 64x64 tile = 512 granules; 2 per thread
#pragma unroll
        for (int it = 0; it < 2; ++it) {
            const int G = it * 256 + tid;
            const int row = G >> 3, gs = G & 7;
            const int gl = gs ^ (row & 7);
            g2l16(A + (size_t)(r0A + row) * 1024 + kk + gl * 8, &sA[(size_t)G * 8]);
        }
        // B: 128x64 tile = 1024 granules; 4 per thread
#pragma unroll
        for (int it = 0; it < 4; ++it) {
            const int G = it * 256 + tid;
            const int row = G >> 3, gs = G & 7;
            const int gl = gs ^ (row & 7);
            g2l16(Bm + (size_t)(r0B + row) * 1024 + kk + gl * 8, &sB[(size_t)G * 8]);
        }
        __syncthreads();

#pragma unroll
        for (int ks = 0; ks < 2; ++ks) {
            short8 a[2], b[4];
#pragma unroll
            for (int i = 0; i < 2; ++i) {
                const int row = wr * 32 + i * 16 + l16;
                const int sg = (ks * 4 + lhi) ^ (row & 7);
                a[i] = *reinterpret_cast<const short8*>(&sA[row * 64 + sg * 8]);
            }
#pragma unroll
            for (int j = 0; j < 4; ++j) {
                const int row = wc * 64 + j * 16 + l16;
                const int sg = (ks * 4 + lhi) ^ (row & 7);
                b[j] = *reinterpret_cast<const short8*>(&sB[row * 64 + sg * 8]);
            }
            if (swp) {
#pragma unroll
                for (int i = 0; i < 2; ++i)
#pragma unroll
                    for (int j = 0; j < 4; ++j)
                        acc[i][j] = MFMA16(b[j], a[i], acc[i][j]);
            } else {
#pragma unroll
                for (int i = 0; i < 2; ++i)
#pragma unroll
                    for (int j = 0; j < 4; ++j)
                        acc[i][j] = MFMA16(a[i], b[j], acc[i][j]);
            }
        }
        __syncthreads();
    }

    __hip_bfloat16* dst = qkv_out + (size_t)mat * 4194304;
    const int mBase = r0A + wr * 32;

    if (swp) {
        // swapped D: row = n (lhi*4+r), col = m (l16) -> 4 consecutive d per lane
        const float qscl = (mat == 0) ? 0.18033688f : 1.0f;  // 0.125*log2e for Q
#pragma unroll
        for (int i = 0; i < 2; ++i) {
            const int mRow = mBase + i * 16 + l16;
            const int bb = mRow >> 11, s = mRow & 2047;
#pragma unroll
            for (int j = 0; j < 4; ++j) {
                const int nCol0 = (nTileBase + j * 16 + lhi * 4) & 1023;
                const int h = nCol0 >> 6, d0 = nCol0 & 63;
                short4_t v4;
#pragma unroll
                for (int r = 0; r < 4; ++r) v4[r] = f2bf(acc[i][j][r] * qscl);
                *reinterpret_cast<short4_t*>(
                    reinterpret_cast<short*>(dst) +
                    (((size_t)(bb * 16 + h) * 2048 + s) << 6) + d0) = v4;
            }
        }
    } else {
        // V transposed per head: [bh][d][s]; lane's 4 r-values = 4 consecutive s
#pragma unroll
        for (int i = 0; i < 2; ++i) {
            const int mRow0 = mBase + i * 16 + lhi * 4;
            const int bb = mRow0 >> 11, s0 = mRow0 & 2047;
#pragma unroll
            for (int j = 0; j < 4; ++j) {
                const int nCol = (nTileBase + j * 16 + l16) & 1023;
                const int h = nCol >> 6, d = nCol & 63;
                short4_t v4;
#pragma unroll
                for (int r = 0; r < 4; ++r) v4[r] = f2bf(acc[i][j][r]);
                *reinterpret_cast<short4_t*>(
                    reinterpret_cast<short*>(dst) +
                    (((size_t)(bb * 16 + h) * 64 + d) << 11) + s0) = v4;
            }
        }
    }
}

// ---------------- Flash attention (causal) — exact R15/R22 (measured best) ----------------
__global__ __launch_bounds__(256, 3) void attn_kernel(
    const __hip_bfloat16* __restrict__ qkv,
    __hip_bfloat16* __restrict__ ctx)
{
    const int tid  = threadIdx.x;
    const int lane = tid & 63;
    const int wid  = tid >> 6;               // 0..3
    const int l16 = lane & 15;
    const int lhi = lane >> 4;

    const int bid = blockIdx.x;              // 512 blocks
    const int xcd = bid & 7, idx = bid >> 3; // idx 0..63
    const int h4 = idx & 3, tg = idx >> 2;   // tg 0..15
    const int bh = xcd * 4 + h4;
    const int g  = (tg < 8) ? (15 - tg) : (tg - 8);  // complementary pairing
    const int q0 = g * 128 + wid * 32;       // wave's 32 rows: [q0, q0+32)
    const int sd = (q0 + 31) >> 6;           // shared diagonal step (both tiles)
    const int ns_blk = 2 * g + 2;

    const short* Q  = reinterpret_cast<const short*>(qkv) + (size_t)bh * 131072;
    const short* K  = Q + 4194304;
    const short* Vt = Q + 8388608;

    __shared__ __align__(16) short sK[2][64 * 64];
    __shared__ __align__(16) short sV[2][64 * 64];

    const int bb = bh >> 4, h = bh & 15;
    const int qrowA = q0 + l16;
    const int qrowB = q0 + 16 + l16;
    const int r7 = l16 & 7;

    short8 qfA[2], qfB[2];
    qfA[0] = *reinterpret_cast<const short8*>(Q + (size_t)qrowA * 64 + lhi * 8);
    qfA[1] = *reinterpret_cast<const short8*>(Q + (size_t)qrowA * 64 + 32 + lhi * 8);
    qfB[0] = *reinterpret_cast<const short8*>(Q + (size_t)qrowB * 64 + lhi * 8);
    qfB[1] = *reinterpret_cast<const short8*>(Q + (size_t)qrowB * 64 + 32 + lhi * 8);

    f32x4 oaccA[4] = {}, oaccB[4] = {};
    float lsumA = 0.0f, lsumB = 0.0f;

    auto stage = [&](int buf, int kv0) {
#pragma unroll
        for (int it = 0; it < 2; ++it) {
            const int G = it * 256 + tid;    // [0,512) granules of 16B
            const int row = G >> 3, gs = G & 7;
            const int gl = gs ^ (row & 7);
            g2l16(K + (size_t)(kv0 + row) * 64 + gl * 8, &sK[buf][(size_t)G * 8]);
            g2l16(Vt + (size_t)row * 2048 + kv0 + gl * 8, &sV[buf][(size_t)G * 8]);
        }
    };

    stage(0, 0);
    asm volatile("s_waitcnt vmcnt(0)" ::: "memory");
    __syncthreads();

    int cur = 0;
#pragma unroll 1
    for (int st = 0; st < ns_blk; ++st) {
        const int kv0 = st * 64;
        if (st + 1 < ns_blk) stage(cur ^ 1, kv0 + 64);

        if (st <= sd) {
            // ---- QK^T swapped, shared K frags: sc*[nt][r] = S[kv][q] ----
            f32x4 scA[4], scB[4];
#pragma unroll
            for (int nt = 0; nt < 4; ++nt) {
                f32x4 sa = {}, sb = {};
#pragma unroll
                for (int ks = 0; ks < 2; ++ks) {
                    const int sg = (ks * 4 + lhi) ^ r7;
                    short8 kb = *reinterpret_cast<const short8*>(
                        &sK[cur][(nt * 16 + l16) * 64 + sg * 8]);
                    sa = MFMA16(kb, qfA[ks], sa);
                    sb = MFMA16(kb, qfB[ks], sb);
                }
                scA[nt] = sa;
                scB[nt] = sb;
            }

            // ---- diagonal mask (shared step) ----
            if (st == sd) {
#pragma unroll
                for (int nt = 0; nt < 4; ++nt) {
                    const int kvb = kv0 + nt * 16 + lhi * 4;
#pragma unroll
                    for (int r = 0; r < 4; ++r) {
                        if (kvb + r > qrowA) scA[nt][r] = -1.0e38f;
                        if (kvb + r > qrowB) scB[nt][r] = -1.0e38f;
                    }
                }
            }

            // ---- P = exp2 in regs; pack; defer row-sums ----
            unsigned pwA[4][2], pwB[4][2];
#pragma unroll
            for (int nt = 0; nt < 4; ++nt) {
                float a0 = exp2f(scA[nt][0]), a1 = exp2f(scA[nt][1]);
                float a2 = exp2f(scA[nt][2]), a3 = exp2f(scA[nt][3]);
                lsumA += (a0 + a1) + (a2 + a3);
                pwA[nt][0] = pack2bf(a0, a1);
                pwA[nt][1] = pack2bf(a2, a3);
                float b0 = exp2f(scB[nt][0]), b1 = exp2f(scB[nt][1]);
                float b2 = exp2f(scB[nt][2]), b3 = exp2f(scB[nt][3]);
                lsumB += (b0 + b1) + (b2 + b3);
                pwB[nt][0] = pack2bf(b0, b1);
                pwB[nt][1] = pack2bf(b2, b3);
            }

            // ---- PV: shared V reads feed both sub-tiles' MFMAs ----
#pragma unroll
            for (int ks = 0; ks < 2; ++ks) {
                uint4v ua, ub;
                ua[0] = pwA[2 * ks][0];     ub[0] = pwB[2 * ks][0];
                ua[1] = pwA[2 * ks][1];     ub[1] = pwB[2 * ks][1];
                ua[2] = pwA[2 * ks + 1][0]; ub[2] = pwB[2 * ks + 1][0];
                ua[3] = pwA[2 * ks + 1][1]; ub[3] = pwB[2 * ks + 1][1];
                short8 paA = u4_to_s8(ua);
                short8 paB = u4_to_s8(ub);
#pragma unroll
                for (int dt = 0; dt < 4; ++dt) {
                    const int row = dt * 16 + l16;
                    const int g0 = (ks * 4 + (lhi >> 1)) ^ (row & 7);
                    const int g1 = (ks * 4 + 2 + (lhi >> 1)) ^ (row & 7);
                    const int sub = (lhi & 1) * 8;
                    const char* base = reinterpret_cast<const char*>(&sV[cur][row * 64]);
                    uint2v lo  = *reinterpret_cast<const uint2v*>(base + g0 * 16 + sub);
                    uint2v hiw = *reinterpret_cast<const uint2v*>(base + g1 * 16 + sub);
                    uint4v uv;
                    uv[0] = lo[0];  uv[1] = lo[1];
                    uv[2] = hiw[0]; uv[3] = hiw[1];
                    short8 vb = u4_to_s8(uv);
                    oaccA[dt] = MFMA16(paA, vb, oaccA[dt]);
                    oaccB[dt] = MFMA16(paB, vb, oaccB[dt]);
                }
            }
        }

        asm volatile("s_waitcnt vmcnt(0)" ::: "memory");
        __syncthreads();
        cur ^= 1;
    }

    // ---- epilogue: row-sum reductions and stores for both sub-tiles ----
    float rsA = lsumA;
    rsA += __shfl_xor(rsA, 16);
    rsA += __shfl_xor(rsA, 32);
    float rsB = lsumB;
    rsB += __shfl_xor(rsB, 16);
    rsB += __shfl_xor(rsB, 32);
    const float riA = 1.0f / rsA;
    const float riB = 1.0f / rsB;
    float rinvA[4], rinvB[4];
#pragma unroll
    for (int r = 0; r < 4; ++r) {
        rinvA[r] = __shfl(riA, lhi * 4 + r);
        rinvB[r] = __shfl(riB, lhi * 4 + r);
    }

#pragma unroll
    for (int dt = 0; dt < 4; ++dt)
#pragma unroll
        for (int r = 0; r < 4; ++r) {
            const int qA = q0 + lhi * 4 + r;
            ctx[((size_t)bb * 2048 + qA) * 1024 + h * 64 + dt * 16 + l16] =
                __float2bfloat16(oaccA[dt][r] * rinvA[r]);
            const int qB = q0 + 16 + lhi * 4 + r;
            ctx[((size_t)bb * 2048 + qB) * 1024 + h * 64 + dt * 16 + l16] =
                __float2bfloat16(oaccB[dt][r] * rinvB[r]);
        }
}

// ---------------- Output projection GEMM + bias (64x128 tiles) — R22 proven ----------------
__global__ __launch_bounds__(256) void out_gemm_kernel(
    const __hip_bfloat16* __restrict__ ctx,
    const __hip_bfloat16* __restrict__ wobf,
    const float* __restrict__ bo,
    float* __restrict__ out)
{
    const int bid = blockIdx.x;
    const int xcd = bid & 7, kb = bid >> 3;       // kb in [0,64)
    const int mBlk = xcd * 8 + (kb >> 3);         // [0,64): 64-row tiles
    const int nBlk = kb & 7;                      // [0,8): 128-col tiles

    const int tid  = threadIdx.x;
    const int lane = tid & 63;
    const int wid  = tid >> 6;
    const int l16  = lane & 15;
    const int lhi  = lane >> 4;
    const int wr = wid >> 1, wc = wid & 1;

    const short* A = reinterpret_cast<const short*>(ctx);
    const short* Bm = reinterpret_cast<const short*>(wobf);
    const int r0A = mBlk * 64, r0B = nBlk * 128;

    __shared__ __align__(16) short sA[64 * 64];
    __shared__ __align__(16) short sB[128 * 64];

    f32x4 acc[2][4] = {};

    for (int kk = 0; kk < 1024; kk += 64) {
#pragma unroll
        for (int it = 0; it < 2; ++it) {
            const int G = it * 256 + tid;
            const int row = G >> 3, gs = G & 7;
            const int gl = gs ^ (row & 7);
            g2l16(A + (size_t)(r0A + row) * 1024 + kk + gl * 8, &sA[(size_t)G * 8]);
        }
#pragma unroll
        for (int it = 0; it < 4; ++it) {
            const int G = it * 256 + tid;
            const int row = G >> 3, gs = G & 7;
            const int gl = gs ^ (row & 7);
            g2l16(Bm + (size_t)(r0B + row) * 1024 + kk + gl * 8, &sB[(size_t)G * 8]);
        }
        __syncthreads();

#pragma unroll
        for (int ks = 0; ks < 2; ++ks) {
            short8 a[2], b[4];
#pragma unroll
            for (int i = 0; i < 2; ++i) {
                const int row = wr * 32 + i * 16 + l16;
                const int sg = (ks * 4 + lhi) ^ (row & 7);
                a[i] = *reinterpret_cast<const short8*>(&sA[row * 64 + sg * 8]);
            }
#pragma unroll
            for (int j = 0; j < 4; ++j) {
                const int row = wc * 64 + j * 16 + l16;
                const int sg = (ks * 4 + lhi) ^ (row & 7);
                b[j] = *reinterpret_cast<const short8*>(&sB[row * 64 + sg * 8]);
            }
#pragma unroll
            for (int i = 0; i < 2; ++i)
#pragma unroll
                for (int j = 0; j < 4; ++j)
                    acc[i][j] = MFMA16(a[i], b[j], acc[i][j]);
        }
        __syncthreads();
    }

    const int mBase = r0A + wr * 32;
    const int nBase = r0B + wc * 64;
#pragma unroll
    for (int i = 0; i < 2; ++i)
#pragma unroll
        for (int j = 0; j < 4; ++j)
#pragma unroll
            for (int r = 0; r < 4; ++r) {
                const int mRow = mBase + i * 16 + lhi * 4 + r;
                const int nCol = nBase + j * 16 + l16;
                out[(size_t)mRow * 1024 + nCol] = acc[i][j][r] + bo[nCol];
            }
}

extern "C" void kernel_launch(void* const* d_in, const int* in_sizes, int n_in,
                              void* d_out, int out_size, void* d_ws, size_t ws_size,
                              hipStream_t stream) {
    const float* x  = (const float*)d_in[0];
    const float* wq = (const float*)d_in[1];
    const float* wk = (const float*)d_in[2];
    const float* wv = (const float*)d_in[3];
    const float* wo = (const float*)d_in[4];
    const float* bo = (const float*)d_in[5];

    __hip_bfloat16* ws = (__hip_bfloat16*)d_ws;
    __hip_bfloat16* ctx  = ws + 12582912;
    __hip_bfloat16* xbf  = ws + 16777216;
    __hip_bfloat16* wqkv = ws + 20971520;
    __hip_bfloat16* wobf = ws + 24117248;
    float* out = (float*)d_out;

    cvt_kernel<<<4096, 256, 0, stream>>>(x, wq, wk, wv, wo, ws);
    qkv_gemm_kernel<<<1536, 256, 0, stream>>>(xbf, wqkv, ws);
    attn_kernel<<<512, 256, 0, stream>>>(ws, ctx);
    out_gemm_kernel<<<512, 256, 0, stream>>>(ctx, wobf, bo, out);
}

// Round 24
// 104.795 us; speedup vs baseline: 1.1891x; 1.0188x over previous
//
#include <hip/hip_runtime.h>
#include <hip/hip_bf16.h>

typedef __attribute__((ext_vector_type(8))) short short8;
typedef __attribute__((ext_vector_type(4))) short short4_t;
typedef __attribute__((ext_vector_type(8))) float f32x8;
typedef __attribute__((ext_vector_type(4))) float f32x4;
typedef __attribute__((ext_vector_type(2))) unsigned uint2v;
typedef __attribute__((ext_vector_type(4))) unsigned uint4v;

#define MFMA16(a, b, c) __builtin_amdgcn_mfma_f32_16x16x32_bf16((a), (b), (c), 0, 0, 0)

// Problem: B=2, S=2048, D=1024, H=16, Dh=64. M = B*S = 4096. Device I/O f32.
// R23 best (106.8 us) + qkv XCD partition transposed: each XCD owns 3 B-panels
// (768KB, L2-resident) x all 64 m-panels, instead of all 24 B-panels (6.3MB >
// 4MB XCD L2 -> thrash). Moves the dominant 393MB B re-read stream L3 -> L2.
// ws layout (bf16 elem offsets):
//   Q    @ 0         [32 bh][2048 s][64 d]   (Q pre-scaled by 0.125*log2e)
//   K    @ 4194304
//   V^T  @ 8388608   [32 bh][64 d][2048 s]
//   ctx  @ 12582912  [4096][1024]
//   xbf  @ 16777216  [4096][1024]
//   wqkv @ 20971520  [3072][1024]
//   wobf @ 24117248  [1024][1024]

static __device__ __forceinline__ short f2bf(float f) {
    __hip_bfloat16 h = __float2bfloat16(f);
    return *reinterpret_cast<short*>(&h);
}

static __device__ __forceinline__ unsigned pack2bf(float lo, float hi) {
    return ((unsigned)f2bf(lo) & 0xffffu) | ((unsigned)f2bf(hi) << 16);
}

static __device__ __forceinline__ short8 u4_to_s8(uint4v u) {
    short8 s;
    __builtin_memcpy(&s, &u, 16);
    return s;
}

static __device__ __forceinline__ void g2l16(const void* g, void* l) {
    __builtin_amdgcn_global_load_lds(
        (const __attribute__((address_space(1))) void*)g,
        (__attribute__((address_space(3))) void*)l,
        16, 0, 0);
}

// ---------------- f32 -> bf16 convert pre-pass ----------------
__global__ __launch_bounds__(256) void cvt_kernel(
    const float* __restrict__ x,  const float* __restrict__ wq,
    const float* __restrict__ wk, const float* __restrict__ wv,
    const float* __restrict__ wo, __hip_bfloat16* __restrict__ ws)
{
    const size_t e = ((size_t)blockIdx.x * 256 + threadIdx.x) * 8;
    const float* src;
    __hip_bfloat16* dst;
    size_t off;
    if (e < 4194304)      { src = x;  dst = ws + 16777216; off = e; }
    else if (e < 5242880) { src = wq; dst = ws + 20971520; off = e - 4194304; }
    else if (e < 6291456) { src = wk; dst = ws + 20971520 + 1048576; off = e - 5242880; }
    else if (e < 7340032) { src = wv; dst = ws + 20971520 + 2097152; off = e - 6291456; }
    else                  { src = wo; dst = ws + 24117248; off = e - 7340032; }

    f32x8 v = *reinterpret_cast<const f32x8*>(src + off);
    short8 o;
#pragma unroll
    for (int j = 0; j < 8; ++j) o[j] = f2bf(v[j]);
    *reinterpret_cast<short8*>(reinterpret_cast<short*>(dst) + off) = o;
}

// ---------------- QKV projection GEMM (bf16, 64x128 tiles, 6 blocks/CU) ----------------
// 1536 blocks x 256 threads. XCD partition: nBlk = xcd*3 + kb%3 (3 B-panels per
// XCD, 768KB L2-resident), mBlk = kb/3 (all 64 m-panels). Block = 64x128; wave
// (wr,wc) owns a 32x64 sub-tile (acc[2][4]). Q/K use swapped MFMA operands.
__global__ __launch_bounds__(256) void qkv_gemm_kernel(
    const __hip_bfloat16* __restrict__ xbf_,
    const __hip_bfloat16* __restrict__ wqkv_,
    __hip_bfloat16* __restrict__ qkv_out)
{
    const int bid = blockIdx.x;
    const int xcd = bid & 7, kb = bid >> 3;       // kb in [0,192)
    const int mBlk = kb / 3;                      // [0,64): 64-row tiles
    const int nBlk = xcd * 3 + (kb % 3);          // [0,24): 128-col tiles

    const int tid  = threadIdx.x;
    const int lane = tid & 63;
    const int wid  = tid >> 6;
    const int l16  = lane & 15;
    const int lhi  = lane >> 4;
    const int wr = wid >> 1, wc = wid & 1;

    const short* A = reinterpret_cast<const short*>(xbf_);
    const short* Bm = reinterpret_cast<const short*>(wqkv_);
    const int r0A = mBlk * 64, r0B = nBlk * 128;

    const int nTileBase = nBlk * 128 + wc * 64;
    const int mat = (nTileBase >> 10);            // block-uniform: 0=q 1=k 2=v
    const bool swp = (mat < 2);

    __shared__ __align__(16) short sA[64 * 64];
    __shared__ __align__(16) short sB[128 * 64];

    f32x4 acc[2][4] = {};

    for (int kk = 0; kk < 1024; kk += 64) {
        // A: 64x64 tile = 512 granules; 2 per thread
#pragma unroll
        for (int it = 0; it < 2; ++it) {
            const int G = it * 256 + tid;
            const int row = G >> 3, gs = G & 7;
            const int gl = gs ^ (row & 7);
            g2l16(A + (size_t)(r0A + row) * 1024 + kk + gl * 8, &sA[(size_t)G * 8]);
        }
        // B: 128x64 tile = 1024 granules; 4 per thread
#pragma unroll
        for (int it = 0; it < 4; ++it) {
            const int G = it * 256 + tid;
            const int row = G >> 3, gs = G & 7;
            const int gl = gs ^ (row & 7);
            g2l16(Bm + (size_t)(r0B + row) * 1024 + kk + gl * 8, &sB[(size_t)G * 8]);
        }
        __syncthreads();

#pragma unroll
        for (int ks = 0; ks < 2; ++ks) {
            short8 a[2], b[4];
#pragma unroll
            for (int i = 0; i < 2; ++i) {
                const int row = wr * 32 + i * 16 + l16;
                const int sg = (ks * 4 + lhi) ^ (row & 7);
                a[i] = *reinterpret_cast<const short8*>(&sA[row * 64 + sg * 8]);
            }
#pragma unroll
            for (int j = 0; j < 4; ++j) {
                const int row = wc * 64 + j * 16 + l16;
                const int sg = (ks * 4 + lhi) ^ (row & 7);
                b[j] = *reinterpret_cast<const short8*>(&sB[row * 64 + sg * 8]);
            }
            if (swp) {
#pragma unroll
                for (int i = 0; i < 2; ++i)
#pragma unroll
                    for (int j = 0; j < 4; ++j)
                        acc[i][j] = MFMA16(b[j], a[i], acc[i][j]);
            } else {
#pragma unroll
                for (int i = 0; i < 2; ++i)
#pragma unroll
                    for (int j = 0; j < 4; ++j)
                        acc[i][j] = MFMA16(a[i], b[j], acc[i][j]);
            }
        }
        __syncthreads();
    }

    __hip_bfloat16* dst = qkv_out + (size_t)mat * 4194304;
    const int mBase = r0A + wr * 32;

    if (swp) {
        // swapped D: row = n (lhi*4+r), col = m (l16) -> 4 consecutive d per lane
        const float qscl = (mat == 0) ? 0.18033688f : 1.0f;  // 0.125*log2e for Q
#pragma unroll
        for (int i = 0; i < 2; ++i) {
            const int mRow = mBase + i * 16 + l16;
            const int bb = mRow >> 11, s = mRow & 2047;
#pragma unroll
            for (int j = 0; j < 4; ++j) {
                const int nCol0 = (nTileBase + j * 16 + lhi * 4) & 1023;
                const int h = nCol0 >> 6, d0 = nCol0 & 63;
                short4_t v4;
#pragma unroll
                for (int r = 0; r < 4; ++r) v4[r] = f2bf(acc[i][j][r] * qscl);
                *reinterpret_cast<short4_t*>(
                    reinterpret_cast<short*>(dst) +
                    (((size_t)(bb * 16 + h) * 2048 + s) << 6) + d0) = v4;
            }
        }
    } else {
        // V transposed per head: [bh][d][s]; lane's 4 r-values = 4 consecutive s
#pragma unroll
        for (int i = 0; i < 2; ++i) {
            const int mRow0 = mBase + i * 16 + lhi * 4;
            const int bb = mRow0 >> 11, s0 = mRow0 & 2047;
#pragma unroll
            for (int j = 0; j < 4; ++j) {
                const int nCol = (nTileBase + j * 16 + l16) & 1023;
                const int h = nCol >> 6, d = nCol & 63;
                short4_t v4;
#pragma unroll
                for (int r = 0; r < 4; ++r) v4[r] = f2bf(acc[i][j][r]);
                *reinterpret_cast<short4_t*>(
                    reinterpret_cast<short*>(dst) +
                    (((size_t)(bb * 16 + h) * 64 + d) << 11) + s0) = v4;
            }
        }
    }
}

// ---------------- Flash attention (causal) — exact R15/R22/R23 (measured best) ----------------
__global__ __launch_bounds__(256, 3) void attn_kernel(
    const __hip_bfloat16* __restrict__ qkv,
    __hip_bfloat16* __restrict__ ctx)
{
    const int tid  = threadIdx.x;
    const int lane = tid & 63;
    const int wid  = tid >> 6;               // 0..3
    const int l16 = lane & 15;
    const int lhi = lane >> 4;

    const int bid = blockIdx.x;              // 512 blocks
    const int xcd = bid & 7, idx = bid >> 3; // idx 0..63
    const int h4 = idx & 3, tg = idx >> 2;   // tg 0..15
    const int bh = xcd * 4 + h4;
    const int g  = (tg < 8) ? (15 - tg) : (tg - 8);  // complementary pairing
    const int q0 = g * 128 + wid * 32;       // wave's 32 rows: [q0, q0+32)
    const int sd = (q0 + 31) >> 6;           // shared diagonal step (both tiles)
    const int ns_blk = 2 * g + 2;

    const short* Q  = reinterpret_cast<const short*>(qkv) + (size_t)bh * 131072;
    const short* K  = Q + 4194304;
    const short* Vt = Q + 8388608;

    __shared__ __align__(16) short sK[2][64 * 64];
    __shared__ __align__(16) short sV[2][64 * 64];

    const int bb = bh >> 4, h = bh & 15;
    const int qrowA = q0 + l16;
    const int qrowB = q0 + 16 + l16;
    const int r7 = l16 & 7;

    short8 qfA[2], qfB[2];
    qfA[0] = *reinterpret_cast<const short8*>(Q + (size_t)qrowA * 64 + lhi * 8);
    qfA[1] = *reinterpret_cast<const short8*>(Q + (size_t)qrowA * 64 + 32 + lhi * 8);
    qfB[0] = *reinterpret_cast<const short8*>(Q + (size_t)qrowB * 64 + lhi * 8);
    qfB[1] = *reinterpret_cast<const short8*>(Q + (size_t)qrowB * 64 + 32 + lhi * 8);

    f32x4 oaccA[4] = {}, oaccB[4] = {};
    float lsumA = 0.0f, lsumB = 0.0f;

    auto stage = [&](int buf, int kv0) {
#pragma unroll
        for (int it = 0; it < 2; ++it) {
            const int G = it * 256 + tid;    // [0,512) granules of 16B
            const int row = G >> 3, gs = G & 7;
            const int gl = gs ^ (row & 7);
            g2l16(K + (size_t)(kv0 + row) * 64 + gl * 8, &sK[buf][(size_t)G * 8]);
            g2l16(Vt + (size_t)row * 2048 + kv0 + gl * 8, &sV[buf][(size_t)G * 8]);
        }
    };

    stage(0, 0);
    asm volatile("s_waitcnt vmcnt(0)" ::: "memory");
    __syncthreads();

    int cur = 0;
#pragma unroll 1
    for (int st = 0; st < ns_blk; ++st) {
        const int kv0 = st * 64;
        if (st + 1 < ns_blk) stage(cur ^ 1, kv0 + 64);

        if (st <= sd) {
            // ---- QK^T swapped, shared K frags: sc*[nt][r] = S[kv][q] ----
            f32x4 scA[4], scB[4];
#pragma unroll
            for (int nt = 0; nt < 4; ++nt) {
                f32x4 sa = {}, sb = {};
#pragma unroll
                for (int ks = 0; ks < 2; ++ks) {
                    const int sg = (ks * 4 + lhi) ^ r7;
                    short8 kb = *reinterpret_cast<const short8*>(
                        &sK[cur][(nt * 16 + l16) * 64 + sg * 8]);
                    sa = MFMA16(kb, qfA[ks], sa);
                    sb = MFMA16(kb, qfB[ks], sb);
                }
                scA[nt] = sa;
                scB[nt] = sb;
            }

            // ---- diagonal mask (shared step) ----
            if (st == sd) {
#pragma unroll
                for (int nt = 0; nt < 4; ++nt) {
                    const int kvb = kv0 + nt * 16 + lhi * 4;
#pragma unroll
                    for (int r = 0; r < 4; ++r) {
                        if (kvb + r > qrowA) scA[nt][r] = -1.0e38f;
                        if (kvb + r > qrowB) scB[nt][r] = -1.0e38f;
                    }
                }
            }

            // ---- P = exp2 in regs; pack; defer row-sums ----
            unsigned pwA[4][2], pwB[4][2];
#pragma unroll
            for (int nt = 0; nt < 4; ++nt) {
                float a0 = exp2f(scA[nt][0]), a1 = exp2f(scA[nt][1]);
                float a2 = exp2f(scA[nt][2]), a3 = exp2f(scA[nt][3]);
                lsumA += (a0 + a1) + (a2 + a3);
                pwA[nt][0] = pack2bf(a0, a1);
                pwA[nt][1] = pack2bf(a2, a3);
                float b0 = exp2f(scB[nt][0]), b1 = exp2f(scB[nt][1]);
                float b2 = exp2f(scB[nt][2]), b3 = exp2f(scB[nt][3]);
                lsumB += (b0 + b1) + (b2 + b3);
                pwB[nt][0] = pack2bf(b0, b1);
                pwB[nt][1] = pack2bf(b2, b3);
            }

            // ---- PV: shared V reads feed both sub-tiles' MFMAs ----
#pragma unroll
            for (int ks = 0; ks < 2; ++ks) {
                uint4v ua, ub;
                ua[0] = pwA[2 * ks][0];     ub[0] = pwB[2 * ks][0];
                ua[1] = pwA[2 * ks][1];     ub[1] = pwB[2 * ks][1];
                ua[2] = pwA[2 * ks + 1][0]; ub[2] = pwB[2 * ks + 1][0];
                ua[3] = pwA[2 * ks + 1][1]; ub[3] = pwB[2 * ks + 1][1];
                short8 paA = u4_to_s8(ua);
                short8 paB = u4_to_s8(ub);
#pragma unroll
                for (int dt = 0; dt < 4; ++dt) {
                    const int row = dt * 16 + l16;
                    const int g0 = (ks * 4 + (lhi >> 1)) ^ (row & 7);
                    const int g1 = (ks * 4 + 2 + (lhi >> 1)) ^ (row & 7);
                    const int sub = (lhi & 1) * 8;
                    const char* base = reinterpret_cast<const char*>(&sV[cur][row * 64]);
                    uint2v lo  = *reinterpret_cast<const uint2v*>(base + g0 * 16 + sub);
                    uint2v hiw = *reinterpret_cast<const uint2v*>(base + g1 * 16 + sub);
                    uint4v uv;
                    uv[0] = lo[0];  uv[1] = lo[1];
                    uv[2] = hiw[0]; uv[3] = hiw[1];
                    short8 vb = u4_to_s8(uv);
                    oaccA[dt] = MFMA16(paA, vb, oaccA[dt]);
                    oaccB[dt] = MFMA16(paB, vb, oaccB[dt]);
                }
            }
        }

        asm volatile("s_waitcnt vmcnt(0)" ::: "memory");
        __syncthreads();
        cur ^= 1;
    }

    // ---- epilogue: row-sum reductions and stores for both sub-tiles ----
    float rsA = lsumA;
    rsA += __shfl_xor(rsA, 16);
    rsA += __shfl_xor(rsA, 32);
    float rsB = lsumB;
    rsB += __shfl_xor(rsB, 16);
    rsB += __shfl_xor(rsB, 32);
    const float riA = 1.0f / rsA;
    const float riB = 1.0f / rsB;
    float rinvA[4], rinvB[4];
#pragma unroll
    for (int r = 0; r < 4; ++r) {
        rinvA[r] = __shfl(riA, lhi * 4 + r);
        rinvB[r] = __shfl(riB, lhi * 4 + r);
    }

#pragma unroll
    for (int dt = 0; dt < 4; ++dt)
#pragma unroll
        for (int r = 0; r < 4; ++r) {
            const int qA = q0 + lhi * 4 + r;
            ctx[((size_t)bb * 2048 + qA) * 1024 + h * 64 + dt * 16 + l16] =
                __float2bfloat16(oaccA[dt][r] * rinvA[r]);
            const int qB = q0 + 16 + lhi * 4 + r;
            ctx[((size_t)bb * 2048 + qB) * 1024 + h * 64 + dt * 16 + l16] =
                __float2bfloat16(oaccB[dt][r] * rinvB[r]);
        }
}

// ---------------- Output projection GEMM + bias (64x128 tiles) — R22 proven ----------------
__global__ __launch_bounds__(256) void out_gemm_kernel(
    const __hip_bfloat16* __restrict__ ctx,
    const __hip_bfloat16* __restrict__ wobf,
    const float* __restrict__ bo,
    float* __restrict__ out)
{
    const int bid = blockIdx.x;
    const int xcd = bid & 7, kb = bid >> 3;       // kb in [0,64)
    const int mBlk = xcd * 8 + (kb >> 3);         // [0,64): 64-row tiles
    const int nBlk = kb & 7;                      // [0,8): 128-col tiles

    const int tid  = threadIdx.x;
    const int lane = tid & 63;
    const int wid  = tid >> 6;
    const int l16  = lane & 15;
    const int lhi  = lane >> 4;
    const int wr = wid >> 1, wc = wid & 1;

    const short* A = reinterpret_cast<const short*>(ctx);
    const short* Bm = reinterpret_cast<const short*>(wobf);
    const int r0A = mBlk * 64, r0B = nBlk * 128;

    __shared__ __align__(16) short sA[64 * 64];
    __shared__ __align__(16) short sB[128 * 64];

    f32x4 acc[2][4] = {};

    for (int kk = 0; kk < 1024; kk += 64) {
#pragma unroll
        for (int it = 0; it < 2; ++it) {
            const int G = it * 256 + tid;
            const int row = G >> 3, gs = G & 7;
            const int gl = gs ^ (row & 7);
            g2l16(A + (size_t)(r0A + row) * 1024 + kk + gl * 8, &sA[(size_t)G * 8]);
        }
#pragma unroll
        for (int it = 0; it < 4; ++it) {
            const int G = it * 256 + tid;
            const int row = G >> 3, gs = G & 7;
            const int gl = gs ^ (row & 7);
            g2l16(Bm + (size_t)(r0B + row) * 1024 + kk + gl * 8, &sB[(size_t)G * 8]);
        }
        __syncthreads();

#pragma unroll
        for (int ks = 0; ks < 2; ++ks) {
            short8 a[2], b[4];
#pragma unroll
            for (int i = 0; i < 2; ++i) {
                const int row = wr * 32 + i * 16 + l16;
                const int sg = (ks * 4 + lhi) ^ (row & 7);
                a[i] = *reinterpret_cast<const short8*>(&sA[row * 64 + sg * 8]);
            }
#pragma unroll
            for (int j = 0; j < 4; ++j) {
                const int row = wc * 64 + j * 16 + l16;
                const int sg = (ks * 4 + lhi) ^ (row & 7);
                b[j] = *reinterpret_cast<const short8*>(&sB[row * 64 + sg * 8]);
            }
#pragma unroll
            for (int i = 0; i < 2; ++i)
#pragma unroll
                for (int j = 0; j < 4; ++j)
                    acc[i][j] = MFMA16(a[i], b[j], acc[i][j]);
        }
        __syncthreads();
    }

    const int mBase = r0A + wr * 32;
    const int nBase = r0B + wc * 64;
#pragma unroll
    for (int i = 0; i < 2; ++i)
#pragma unroll
        for (int j = 0; j < 4; ++j)
#pragma unroll
            for (int r = 0; r < 4; ++r) {
                const int mRow = mBase + i * 16 + lhi * 4 + r;
                const int nCol = nBase + j * 16 + l16;
                out[(size_t)mRow * 1024 + nCol] = acc[i][j][r] + bo[nCol];
            }
}

extern "C" void kernel_launch(void* const* d_in, const int* in_sizes, int n_in,
                              void* d_out, int out_size, void* d_ws, size_t ws_size,
                              hipStream_t stream) {
    const float* x  = (const float*)d_in[0];
    const float* wq = (const float*)d_in[1];
    const float* wk = (const float*)d_in[2];
    const float* wv = (const float*)d_in[3];
    const float* wo = (const float*)d_in[4];
    const float* bo = (const float*)d_in[5];

    __hip_bfloat16* ws = (__hip_bfloat16*)d_ws;
    __hip_bfloat16* ctx  = ws + 12582912;
    __hip_bfloat16* xbf  = ws + 16777216;
    __hip_bfloat16* wqkv = ws + 20971520;
    __hip_bfloat16* wobf = ws + 24117248;
    float* out = (float*)d_out;

    cvt_kernel<<<4096, 256, 0, stream>>>(x, wq, wk, wv, wo, ws);
    qkv_gemm_kernel<<<1536, 256, 0, stream>>>(xbf, wqkv, ws);
    attn_kernel<<<512, 256, 0, stream>>>(ws, ctx);
    out_gemm_kernel<<<512, 256, 0, stream>>>(ctx, wobf, bo, out);
}